// Round 11
// baseline (525.826 us; speedup 1.0000x reference)
//
#include <hip/hip_runtime.h>
#include <hip/hip_cooperative_groups.h>
#include <cstdint>
#include <cstddef>

namespace cg = cooperative_groups;

#define NNODES 100000
#define NEDGES 1600000
#define NWIN 100
#define WIN_NODES 1000
#define WCAP 17408
#define WSTR 16

#define GM_ROWS 128
#define APAD 72
#define GEMM_TILES ((NNODES + GM_ROWS - 1) / GM_ROWS)   // 782
#define SMEMSZ 27648                                     // GEMM As+Bs (max phase)

typedef __attribute__((ext_vector_type(8))) short bf16x8;
typedef __attribute__((ext_vector_type(4))) float f32x4;
typedef __attribute__((ext_vector_type(8))) unsigned short ushort8v;

__device__ inline unsigned short f2bf(float f) {
    union { float f; unsigned u; } v; v.f = f;
    unsigned r = v.u + 0x7FFFu + ((v.u >> 16) & 1u);   // RNE
    return (unsigned short)(r >> 16);
}
__device__ inline void bfpair(unsigned u, float& lo, float& hi) {
    union { unsigned x; float f; } a, b;
    a.x = u << 16; b.x = u & 0xffff0000u;
    lo = a.f; hi = b.f;
}

struct GArgs {
    const float* x; const unsigned short* Wt; unsigned short* Hs1;
    const int* src; const int* dst; unsigned* stage; int* wcur;
    int* rowstart; float* dinv; int* csr;
    const float* b1; const float* W2; unsigned short* Hs2;
    const float* b2; unsigned short* r2s;
    const float* W3; const float* b3; float* out;
    int nbucket;
};

// ---------------- W1 convert+transpose (+ wcur zero) ----------------

__global__ __launch_bounds__(256) void convW(const float* __restrict__ W,
                                             unsigned short* __restrict__ Wt,
                                             int* __restrict__ wcur) {
    if (blockIdx.x == 0 && threadIdx.x < NWIN) wcur[threadIdx.x * WSTR] = 0;
    int i = blockIdx.x * 256 + threadIdx.x;
    if (i < 512 * 64) {
        int k = i >> 6, n = i & 63;
        Wt[n * 512 + k] = f2bf(W[i]);
    }
}

// ---------------- phase A: GEMM tile (1-deep reg prefetch) ----------------

__device__ __forceinline__ void gemm_tile(const float* __restrict__ A,
        const unsigned short* __restrict__ Wt, unsigned short* __restrict__ Hs,
        int g, char* smem) {
    typedef unsigned short RowA[APAD];
    RowA* As = (RowA*)smem;                 // [128][72]
    RowA* Bs = (RowA*)(smem + 18432);       // [64][72]
    const int tid = threadIdx.x;
    const int wid = tid >> 6;
    const int lane = tid & 63;
    const int bm = g * GM_ROWS;

    f32x4 acc[2][4];
#pragma unroll
    for (int i = 0; i < 2; i++)
#pragma unroll
        for (int j = 0; j < 4; j++) acc[i][j] = (f32x4){0.f, 0.f, 0.f, 0.f};

    const int ar = tid >> 4;
    const int ac4 = tid & 15;
    const int lm = lane & 15;
    const int lk = (lane >> 4) * 8;

    float4 aR[8];
    ushort8v bR[2];

    auto LOAD = [&](int k0) {
#pragma unroll
        for (int p = 0; p < 8; p++) {
            int row = bm + p * 16 + ar;
            if (row < NNODES) aR[p] = *(const float4*)&A[(size_t)row * 512 + k0 + ac4 * 4];
            else              aR[p] = make_float4(0.f, 0.f, 0.f, 0.f);
        }
#pragma unroll
        for (int p = 0; p < 2; p++) {
            int c = p * 256 + tid;
            int n = c >> 3, kc = c & 7;
            bR[p] = *(const ushort8v*)&Wt[(size_t)n * 512 + k0 + kc * 8];
        }
    };

    LOAD(0);
    for (int k0 = 0; k0 < 512; k0 += 64) {
#pragma unroll
        for (int p = 0; p < 8; p++) {
            int r = p * 16 + ar;
            unsigned lo, hi;
            asm("v_cvt_pk_bf16_f32 %0, %1, %2" : "=v"(lo) : "v"(aR[p].x), "v"(aR[p].y));
            asm("v_cvt_pk_bf16_f32 %0, %1, %2" : "=v"(hi) : "v"(aR[p].z), "v"(aR[p].w));
            uint2 u; u.x = lo; u.y = hi;
            *(uint2*)&As[r][ac4 * 4] = u;
        }
#pragma unroll
        for (int p = 0; p < 2; p++) {
            int c = p * 256 + tid;
            int n = c >> 3, kc = c & 7;
            *(ushort8v*)&Bs[n][kc * 8] = bR[p];
        }
        __syncthreads();

        if (k0 + 64 < 512) LOAD(k0 + 64);

        bf16x8 af[2][2], bf[4][2];
#pragma unroll
        for (int rf = 0; rf < 2; rf++)
#pragma unroll
            for (int kf = 0; kf < 2; kf++)
                af[rf][kf] = *(const bf16x8*)&As[wid * 32 + rf * 16 + lm][kf * 32 + lk];
#pragma unroll
        for (int cf = 0; cf < 4; cf++)
#pragma unroll
            for (int kf = 0; kf < 2; kf++)
                bf[cf][kf] = *(const bf16x8*)&Bs[cf * 16 + lm][kf * 32 + lk];

#pragma unroll
        for (int kf = 0; kf < 2; kf++)
#pragma unroll
            for (int rf = 0; rf < 2; rf++)
#pragma unroll
                for (int cf = 0; cf < 4; cf++)
                    acc[rf][cf] = __builtin_amdgcn_mfma_f32_16x16x32_bf16(
                        af[rf][kf], bf[cf][kf], acc[rf][cf], 0, 0, 0);
        __syncthreads();
    }

#pragma unroll
    for (int rf = 0; rf < 2; rf++) {
#pragma unroll
        for (int j = 0; j < 4; j++) {
            int row = bm + wid * 32 + rf * 16 + (lane >> 4) * 4 + j;
            if (row < NNODES) {
#pragma unroll
                for (int cf = 0; cf < 4; cf++)
                    Hs[(size_t)row * 64 + cf * 16 + lm] = f2bf(acc[rf][cf][j]);
            }
        }
    }
}

__device__ __forceinline__ void bucket_chunk(const int* __restrict__ src,
        const int* __restrict__ dst, unsigned* __restrict__ stage,
        int* __restrict__ wcur, int e0, int e1, char* smem) {
    int* cnt  = (int*)smem;
    int* lcur = cnt + NWIN;
    const int tid = threadIdx.x;
    for (int i = tid; i < NWIN; i += 256) cnt[i] = 0;
    __syncthreads();
    for (int e = e0 + tid; e < e1; e += 256)
        atomicAdd(&cnt[dst[e] / WIN_NODES], 1);
    __syncthreads();
    for (int i = tid; i < NWIN; i += 256)
        lcur[i] = atomicAdd(&wcur[i * WSTR], cnt[i]);
    __syncthreads();
    for (int e = e0 + tid; e < e1; e += 256) {
        int d = dst[e], s = src[e];
        int w = d / WIN_NODES;
        int pos = atomicAdd(&lcur[w], 1);
        if (pos < WCAP)
            stage[(size_t)w * WCAP + pos] =
                ((unsigned)(d - w * WIN_NODES) << 17) | (unsigned)s;
    }
}

__device__ __forceinline__ void phaseA(const GArgs& a, char* smem) {
    int nb = a.nbucket;
    int ng = (int)gridDim.x - nb;
    int bid = (int)blockIdx.x;
    if (bid < ng) {
        for (int g = bid; g < GEMM_TILES; g += ng)
            gemm_tile(a.x, a.Wt, a.Hs1, g, smem);
    } else {
        int bi = bid - ng;
        int chunk = (NEDGES + nb - 1) / nb;
        int e0 = bi * chunk;
        int e1 = e0 + chunk; if (e1 > NEDGES) e1 = NEDGES;
        bucket_chunk(a.src, a.dst, a.stage, a.wcur, e0, e1, smem);
    }
}

// ---------------- phase B: csr_window ----------------

__device__ __forceinline__ void csr_win(const GArgs& a, int w, char* smem) {
    int* cnt = (int*)smem;                 // 1000 ints
    int* red = (int*)(smem + 4096);        // 256 ints
    const int t = threadIdx.x;
    const int wb = w * WIN_NODES;
    const size_t sb = (size_t)w * WCAP;

    int v = (t < w) ? min(a.wcur[t * WSTR], WCAP) : 0;
    red[t] = v;
    __syncthreads();
#pragma unroll
    for (int off = 128; off > 0; off >>= 1) {
        if (t < off) red[t] += red[t + off];
        __syncthreads();
    }
    int woff = red[0];
    int n_w = min(a.wcur[w * WSTR], WCAP);
    __syncthreads();

    for (int i = t; i < WIN_NODES; i += 256) cnt[i] = 0;
    __syncthreads();
    for (int i = t; i < n_w; i += 256)
        atomicAdd(&cnt[a.stage[sb + i] >> 17], 1);
    __syncthreads();

    int c0 = 0, c1 = 0, c2 = 0, c3 = 0, psum = 0;
    if (t < 250) {
        c0 = cnt[4 * t]; c1 = cnt[4 * t + 1]; c2 = cnt[4 * t + 2]; c3 = cnt[4 * t + 3];
        psum = c0 + c1 + c2 + c3;
    }
    red[t] = psum;
    __syncthreads();
#pragma unroll
    for (int off = 1; off < 256; off <<= 1) {
        int tv = (t >= off) ? red[t - off] : 0;
        __syncthreads();
        red[t] += tv;
        __syncthreads();
    }
    int excl = red[t] - psum;
    if (t < 250) {
        int running = woff + excl;
        int idx = 4 * t;
        a.rowstart[wb + idx] = running; a.dinv[wb + idx] = rsqrtf((float)c0 + 1.f);
        cnt[idx] = running; running += c0;
        a.rowstart[wb + idx + 1] = running; a.dinv[wb + idx + 1] = rsqrtf((float)c1 + 1.f);
        cnt[idx + 1] = running; running += c1;
        a.rowstart[wb + idx + 2] = running; a.dinv[wb + idx + 2] = rsqrtf((float)c2 + 1.f);
        cnt[idx + 2] = running; running += c2;
        a.rowstart[wb + idx + 3] = running; a.dinv[wb + idx + 3] = rsqrtf((float)c3 + 1.f);
        cnt[idx + 3] = running;
    }
    if (w == NWIN - 1 && t == 0) a.rowstart[NNODES] = woff + n_w;
    __syncthreads();

    for (int i = t; i < n_w; i += 256) {
        unsigned p = a.stage[sb + i];
        int dl = (int)(p >> 17);
        int s  = (int)(p & 0x1FFFFu);
        int pos = atomicAdd(&cnt[dl], 1);
        a.csr[pos] = s;
    }
}

__device__ __forceinline__ void phaseB(const GArgs& a, char* smem) {
    for (int w = blockIdx.x; w < NWIN; w += gridDim.x) csr_win(a, w, smem);
}

// ---------------- phase C: gather64 (per-edge dinv) + fused 64->16 ----------------

__device__ __forceinline__ void phaseC(const GArgs& a, char* smem) {
    float* Ws2 = (float*)smem;                       // 4096
    float* b1s = (float*)(smem + 4096);              // 256
    typedef float Row68[68];
    Row68* srow = (Row68*)(smem + 4352);             // 16*68*4 = 4352
    for (int i = threadIdx.x; i < 64 * 16; i += 256) Ws2[i] = a.W2[i];
    if (threadIdx.x < 64) b1s[threadIdx.x] = a.b1[threadIdx.x];
    __syncthreads();

    const int r = threadIdx.x >> 4;
    const int lf = threadIdx.x & 15;
    const int ngrp = (NNODES + 15) / 16;
    const uint2* H8 = (const uint2*)a.Hs1;

    for (int grp = blockIdx.x; grp < ngrp; grp += gridDim.x) {
        int row = grp * 16 + r;
        bool rok = (row < NNODES);
        float a0 = 0.f, a1 = 0.f, a2 = 0.f, a3 = 0.f;
        float dd = 0.f;
        if (rok) {
            int e0 = a.rowstart[row], e1 = a.rowstart[row + 1];
            dd = a.dinv[row];
            uint2 u = H8[(size_t)row * 16 + lf];
            bfpair(u.x, a0, a1); bfpair(u.y, a2, a3);
            a0 *= dd; a1 *= dd; a2 *= dd; a3 *= dd;
            int e = e0;
            for (; e + 3 < e1; e += 4) {
                int s0 = a.csr[e], s1 = a.csr[e+1], s2 = a.csr[e+2], s3 = a.csr[e+3];
                float w0 = a.dinv[s0], w1 = a.dinv[s1], w2 = a.dinv[s2], w3 = a.dinv[s3];
                uint2 u0 = H8[(size_t)s0 * 16 + lf];
                uint2 u1 = H8[(size_t)s1 * 16 + lf];
                uint2 u2 = H8[(size_t)s2 * 16 + lf];
                uint2 u3 = H8[(size_t)s3 * 16 + lf];
                float x0, x1;
                bfpair(u0.x, x0, x1); a0 += w0 * x0; a1 += w0 * x1;
                bfpair(u0.y, x0, x1); a2 += w0 * x0; a3 += w0 * x1;
                bfpair(u1.x, x0, x1); a0 += w1 * x0; a1 += w1 * x1;
                bfpair(u1.y, x0, x1); a2 += w1 * x0; a3 += w1 * x1;
                bfpair(u2.x, x0, x1); a0 += w2 * x0; a1 += w2 * x1;
                bfpair(u2.y, x0, x1); a2 += w2 * x0; a3 += w2 * x1;
                bfpair(u3.x, x0, x1); a0 += w3 * x0; a1 += w3 * x1;
                bfpair(u3.y, x0, x1); a2 += w3 * x0; a3 += w3 * x1;
            }
            for (; e < e1; e++) {
                int s0 = a.csr[e];
                float w0 = a.dinv[s0];
                uint2 ue = H8[(size_t)s0 * 16 + lf];
                float x0, x1;
                bfpair(ue.x, x0, x1); a0 += w0 * x0; a1 += w0 * x1;
                bfpair(ue.y, x0, x1); a2 += w0 * x0; a3 += w0 * x1;
            }
            a0 = fmaxf(a0 * dd + b1s[4 * lf + 0], 0.f);
            a1 = fmaxf(a1 * dd + b1s[4 * lf + 1], 0.f);
            a2 = fmaxf(a2 * dd + b1s[4 * lf + 2], 0.f);
            a3 = fmaxf(a3 * dd + b1s[4 * lf + 3], 0.f);
        }
        float4 t4; t4.x = a0; t4.y = a1; t4.z = a2; t4.w = a3;
        *(float4*)&srow[r][4 * lf] = t4;
        __syncthreads();

        if (rok) {
            float acc = 0.f;
#pragma unroll
            for (int k4 = 0; k4 < 16; k4++) {
                float4 s4 = *(const float4*)&srow[r][k4 * 4];
                acc += s4.x * Ws2[(k4 * 4 + 0) * 16 + lf];
                acc += s4.y * Ws2[(k4 * 4 + 1) * 16 + lf];
                acc += s4.z * Ws2[(k4 * 4 + 2) * 16 + lf];
                acc += s4.w * Ws2[(k4 * 4 + 3) * 16 + lf];
            }
            acc *= dd;
            float hi = __shfl_down(acc, 1, 64);
            if ((lf & 1) == 0) {
                unsigned p = (unsigned)f2bf(acc) | ((unsigned)f2bf(hi) << 16);
                ((unsigned*)a.Hs2)[(size_t)row * 8 + (lf >> 1)] = p;
            }
        }
        __syncthreads();
    }
}

// ---------------- phase D: layer-2 aggregation ----------------

__device__ __forceinline__ void phaseD(const GArgs& a, char* smem) {
    float* bs = (float*)smem;
    if (threadIdx.x < 16) bs[threadIdx.x] = a.b2[threadIdx.x];
    __syncthreads();

    const int r = threadIdx.x >> 2;
    const int lf = threadIdx.x & 3;
    const int ngrp = (NNODES + 63) / 64;
    const uint2* H8 = (const uint2*)a.Hs2;

    for (int grp = blockIdx.x; grp < ngrp; grp += gridDim.x) {
        int row = grp * 64 + r;
        if (row >= NNODES) continue;
        int e0 = a.rowstart[row], e1 = a.rowstart[row + 1];
        uint2 u = H8[(size_t)row * 4 + lf];
        float a0, a1, a2, a3;
        bfpair(u.x, a0, a1); bfpair(u.y, a2, a3);
        int e = e0;
        for (; e + 3 < e1; e += 4) {
            int s0 = a.csr[e], s1 = a.csr[e+1], s2 = a.csr[e+2], s3 = a.csr[e+3];
            uint2 u0 = H8[(size_t)s0 * 4 + lf];
            uint2 u1 = H8[(size_t)s1 * 4 + lf];
            uint2 u2 = H8[(size_t)s2 * 4 + lf];
            uint2 u3 = H8[(size_t)s3 * 4 + lf];
            float x0, x1;
            bfpair(u0.x, x0, x1); a0 += x0; a1 += x1;
            bfpair(u0.y, x0, x1); a2 += x0; a3 += x1;
            bfpair(u1.x, x0, x1); a0 += x0; a1 += x1;
            bfpair(u1.y, x0, x1); a2 += x0; a3 += x1;
            bfpair(u2.x, x0, x1); a0 += x0; a1 += x1;
            bfpair(u2.y, x0, x1); a2 += x0; a3 += x1;
            bfpair(u3.x, x0, x1); a0 += x0; a1 += x1;
            bfpair(u3.y, x0, x1); a2 += x0; a3 += x1;
        }
        for (; e < e1; e++) {
            uint2 ue = H8[(size_t)a.csr[e] * 4 + lf];
            float x0, x1;
            bfpair(ue.x, x0, x1); a0 += x0; a1 += x1;
            bfpair(ue.y, x0, x1); a2 += x0; a3 += x1;
        }
        float dd = a.dinv[row];
        a0 = fmaxf(a0 * dd + bs[4 * lf + 0], 0.f) * dd;
        a1 = fmaxf(a1 * dd + bs[4 * lf + 1], 0.f) * dd;
        a2 = fmaxf(a2 * dd + bs[4 * lf + 2], 0.f) * dd;
        a3 = fmaxf(a3 * dd + bs[4 * lf + 3], 0.f) * dd;
        uint2 p;
        p.x = (unsigned)f2bf(a0) | ((unsigned)f2bf(a1) << 16);
        p.y = (unsigned)f2bf(a2) | ((unsigned)f2bf(a3) << 16);
        ((uint2*)a.r2s)[(size_t)row * 4 + lf] = p;
    }
}

// ---------------- phase E: layer-3 agg + 16->40 matvec + log_softmax ----------------

__device__ __forceinline__ void phaseE(const GArgs& a, char* smem) {
    float* Ws3 = (float*)smem;                        // 2560
    float* bs3 = (float*)(smem + 2560);               // 160
    typedef float Row20[20];
    Row20* srow = (Row20*)(smem + 2720);              // 64*20*4 = 5120
    float* orow = (float*)(smem + 7840);              // 64*40*4 = 10240
    for (int i = threadIdx.x; i < 16 * 40; i += 256) Ws3[i] = a.W3[i];
    if (threadIdx.x < 40) bs3[threadIdx.x] = a.b3[threadIdx.x];
    __syncthreads();

    const int r = threadIdx.x >> 2;
    const int lf = threadIdx.x & 3;
    const int ngrp = (NNODES + 63) / 64;
    const uint2* H8 = (const uint2*)a.r2s;

    for (int grp = blockIdx.x; grp < ngrp; grp += gridDim.x) {
        int row = grp * 64 + r;
        bool rok = (row < NNODES);
        float a0 = 0.f, a1 = 0.f, a2 = 0.f, a3 = 0.f;
        if (rok) {
            int e0 = a.rowstart[row], e1 = a.rowstart[row + 1];
            uint2 u = H8[(size_t)row * 4 + lf];
            bfpair(u.x, a0, a1); bfpair(u.y, a2, a3);
            int e = e0;
            for (; e + 3 < e1; e += 4) {
                int s0 = a.csr[e], s1 = a.csr[e+1], s2 = a.csr[e+2], s3 = a.csr[e+3];
                uint2 u0 = H8[(size_t)s0 * 4 + lf];
                uint2 u1 = H8[(size_t)s1 * 4 + lf];
                uint2 u2 = H8[(size_t)s2 * 4 + lf];
                uint2 u3 = H8[(size_t)s3 * 4 + lf];
                float x0, x1;
                bfpair(u0.x, x0, x1); a0 += x0; a1 += x1;
                bfpair(u0.y, x0, x1); a2 += x0; a3 += x1;
                bfpair(u1.x, x0, x1); a0 += x0; a1 += x1;
                bfpair(u1.y, x0, x1); a2 += x0; a3 += x1;
                bfpair(u2.x, x0, x1); a0 += x0; a1 += x1;
                bfpair(u2.y, x0, x1); a2 += x0; a3 += x1;
                bfpair(u3.x, x0, x1); a0 += x0; a1 += x1;
                bfpair(u3.y, x0, x1); a2 += x0; a3 += x1;
            }
            for (; e < e1; e++) {
                uint2 ue = H8[(size_t)a.csr[e] * 4 + lf];
                float x0, x1;
                bfpair(ue.x, x0, x1); a0 += x0; a1 += x1;
                bfpair(ue.y, x0, x1); a2 += x0; a3 += x1;
            }
            float dd = a.dinv[row];
            a0 *= dd; a1 *= dd; a2 *= dd; a3 *= dd;
        }
        float4 t4; t4.x = a0; t4.y = a1; t4.z = a2; t4.w = a3;
        *(float4*)&srow[r][4 * lf] = t4;
        __syncthreads();

        float vals[10];
#pragma unroll
        for (int q = 0; q < 10; q++) vals[q] = bs3[lf + 4 * q];
#pragma unroll
        for (int k4 = 0; k4 < 4; k4++) {
            float4 s4 = *(const float4*)&srow[r][k4 * 4];
#pragma unroll
            for (int q = 0; q < 10; q++) {
                int n = lf + 4 * q;
                vals[q] += s4.x * Ws3[(k4 * 4 + 0) * 40 + n];
                vals[q] += s4.y * Ws3[(k4 * 4 + 1) * 40 + n];
                vals[q] += s4.z * Ws3[(k4 * 4 + 2) * 40 + n];
                vals[q] += s4.w * Ws3[(k4 * 4 + 3) * 40 + n];
            }
        }
        float m = vals[0];
#pragma unroll
        for (int q = 1; q < 10; q++) m = fmaxf(m, vals[q]);
#pragma unroll
        for (int off = 1; off < 4; off <<= 1) m = fmaxf(m, __shfl_xor(m, off, 64));
        float s = 0.f;
#pragma unroll
        for (int q = 0; q < 10; q++) s += expf(vals[q] - m);
#pragma unroll
        for (int off = 1; off < 4; off <<= 1) s += __shfl_xor(s, off, 64);
        float ls = logf(s) + m;
#pragma unroll
        for (int q = 0; q < 10; q++) orow[r * 40 + lf + 4 * q] = vals[q] - ls;
        __syncthreads();

        float4* o4 = (float4*)(a.out + (size_t)grp * 64 * 40);
        const float4* s4p = (const float4*)orow;
        for (int i = threadIdx.x; i < 640; i += 256) {
            int rr = (i * 4) / 40;
            if (grp * 64 + rr < NNODES) o4[i] = s4p[i];
        }
        __syncthreads();
    }
}

// ---------------- fused cooperative kernel ----------------

__global__ __launch_bounds__(256, 4) void fused_gcn(GArgs a) {
    __shared__ __align__(16) char smem[SMEMSZ];
    cg::grid_group grid = cg::this_grid();
    phaseA(a, smem);
    grid.sync();
    phaseB(a, smem);
    grid.sync();
    phaseC(a, smem);
    grid.sync();
    phaseD(a, smem);
    grid.sync();
    phaseE(a, smem);
}

// ---------------- fallback standalone kernels (non-cooperative path) ----------------

__global__ __launch_bounds__(256, 4) void kA(GArgs a) {
    __shared__ __align__(16) char smem[SMEMSZ];
    phaseA(a, smem);
}
__global__ __launch_bounds__(256, 4) void kB(GArgs a) {
    __shared__ __align__(16) char smem[SMEMSZ];
    phaseB(a, smem);
}
__global__ __launch_bounds__(256, 4) void kC(GArgs a) {
    __shared__ __align__(16) char smem[SMEMSZ];
    phaseC(a, smem);
}
__global__ __launch_bounds__(256, 4) void kD(GArgs a) {
    __shared__ __align__(16) char smem[SMEMSZ];
    phaseD(a, smem);
}
__global__ __launch_bounds__(256, 4) void kE(GArgs a) {
    __shared__ __align__(16) char smem[SMEMSZ];
    phaseE(a, smem);
}

// ---------------- launch ----------------

extern "C" void kernel_launch(void* const* d_in, const int* in_sizes, int n_in,
                              void* d_out, int out_size, void* d_ws, size_t ws_size,
                              hipStream_t stream) {
    const float* x   = (const float*)d_in[0];
    const int*   ei  = (const int*)d_in[1];
    const float* W1 = (const float*)d_in[2];
    const float* b1 = (const float*)d_in[3];
    const float* W2 = (const float*)d_in[4];
    const float* b2 = (const float*)d_in[5];
    const float* W3 = (const float*)d_in[6];
    const float* b3 = (const float*)d_in[7];

    int* ws_i = (int*)d_ws;
    int* wcur     = ws_i;                        // NWIN*WSTR
    int* rowstart = wcur + NWIN * WSTR + 16;     // N+8
    int* csr      = rowstart + NNODES + 8;       // E
    unsigned* stage = (unsigned*)(csr + NEDGES); // NWIN*WCAP
    float* dinv   = (float*)(stage + (size_t)NWIN * WCAP);  // N
    unsigned short* Wt = (unsigned short*)(dinv + NNODES);  // 64*512
    float* bufA   = (float*)((int*)(Wt + 64 * 512) + 16);
    float* bufB   = bufA + (size_t)NNODES * 64;

    GArgs a;
    a.x = x; a.Wt = Wt; a.Hs1 = (unsigned short*)bufA;
    a.src = ei; a.dst = ei + NEDGES; a.stage = stage; a.wcur = wcur;
    a.rowstart = rowstart; a.dinv = dinv; a.csr = csr;
    a.b1 = b1; a.W2 = W2; a.Hs2 = (unsigned short*)bufB;
    a.b2 = b2; a.r2s = (unsigned short*)bufA;    // Hs1 dead after phase C
    a.W3 = W3; a.b3 = b3; a.out = (float*)d_out;

    convW<<<128, 256, 0, stream>>>(W1, Wt, wcur);

    int maxB = 0;
    hipError_t qerr = hipOccupancyMaxActiveBlocksPerMultiprocessor(&maxB, fused_gcn, 256, 0);

    hipError_t lerr = hipErrorUnknown;
    if (qerr == hipSuccess && maxB >= 1) {
        int grid = maxB * 256;
        if (grid > 1024) grid = 1024;
        if (grid >= 256) {
            a.nbucket = grid / 4;
            void* params[] = { (void*)&a };
            lerr = hipLaunchCooperativeKernel((const void*)fused_gcn,
                                              dim3(grid), dim3(256), params, 0, stream);
        }
    }

    if (lerr != hipSuccess) {
        // fallback: 5-kernel non-cooperative pipeline (same phase code)
        a.nbucket = 256;
        kA<<<1024, 256, 0, stream>>>(a);
        kB<<<NWIN, 256, 0, stream>>>(a);
        kC<<<(NNODES + 15) / 16, 256, 0, stream>>>(a);
        kD<<<(NNODES + 63) / 64, 256, 0, stream>>>(a);
        kE<<<(NNODES + 63) / 64, 256, 0, stream>>>(a);
    }
}

// Round 12
// 233.934 us; speedup vs baseline: 2.2478x; 2.2478x over previous
//
#include <hip/hip_runtime.h>
#include <cstdint>
#include <cstddef>

#define NNODES 100000
#define NEDGES 1600000
#define NWIN 100
#define WIN_NODES 1000
#define WCAP 17408
#define WSTR 16

#define GM_ROWS 128
#define GEMM_BLOCKS ((NNODES + GM_ROWS - 1) / GM_ROWS)   // 782
#define BUCKET_BLOCKS 512
#define BCHUNK ((NEDGES + BUCKET_BLOCKS - 1) / BUCKET_BLOCKS)  // 3125
#define MEGA_BLOCKS (GEMM_BLOCKS + BUCKET_BLOCKS)        // 1294

typedef __attribute__((ext_vector_type(8))) short bf16x8;
typedef __attribute__((ext_vector_type(4))) float f32x4;

__device__ inline unsigned short f2bf(float f) {
    union { float f; unsigned u; } v; v.f = f;
    unsigned r = v.u + 0x7FFFu + ((v.u >> 16) & 1u);   // RNE
    return (unsigned short)(r >> 16);
}
__device__ inline void bfpair(unsigned u, float& lo, float& hi) {
    union { unsigned x; float f; } a, b;
    a.x = u << 16; b.x = u & 0xffff0000u;
    lo = a.f; hi = b.f;
}

// ---------------- W1 convert+transpose (+ wcur zero) ----------------

__global__ __launch_bounds__(256) void convW(const float* __restrict__ W,
                                             unsigned short* __restrict__ Wt,
                                             int* __restrict__ wcur) {
    if (blockIdx.x == 0 && threadIdx.x < NWIN) wcur[threadIdx.x * WSTR] = 0;
    int i = blockIdx.x * 256 + threadIdx.x;
    if (i < 512 * 64) {
        int k = i >> 6, n = i & 63;
        Wt[n * 512 + k] = f2bf(W[i]);
    }
}

// ---------------- MEGA kernel: LDS-free GEMM role + edge-bucketing role ----------------
// GEMM role: each wave owns 32 rows x 64 cols; A-fragments loaded DIRECT from
// global (coalesced: lanes 0..31 cover 16 full 64B lines) and converted
// f32->bf16 in-register; B-fragments direct from bf16 Wt (L2-hot 64KB).
// No LDS, no barriers -> occupancy VGPR-bound, latency hidden by TLP.

__global__ __launch_bounds__(256) void mega_gemm_bucket(
        const float* __restrict__ A,            // [M,512] x
        const unsigned short* __restrict__ Wt,  // [64][512] bf16
        unsigned short* __restrict__ Hs,        // [M,64] bf16 UNSCALED out
        const int* __restrict__ src, const int* __restrict__ dst,
        unsigned* __restrict__ stage,
        int* __restrict__ wcur, int M, int E) {
    __shared__ int smem_cnt[NWIN];
    __shared__ int smem_lcur[NWIN];

    long long b = blockIdx.x;
    int g0 = (int)((b * GEMM_BLOCKS) / MEGA_BLOCKS);
    int g1 = (int)(((b + 1) * GEMM_BLOCKS) / MEGA_BLOCKS);

    if (g1 > g0) {
        // ---------------- GEMM role (LDS-free) ----------------
        const int tid = threadIdx.x;
        const int wid = tid >> 6;
        const int lane = tid & 63;
        const int lm = lane & 15;
        const int lk = (lane >> 4) * 8;        // k offset within 32-step
        const int bm = g0 * GM_ROWS;

        f32x4 acc[2][4];
#pragma unroll
        for (int i = 0; i < 2; i++)
#pragma unroll
            for (int j = 0; j < 4; j++) acc[i][j] = (f32x4){0.f, 0.f, 0.f, 0.f};

        // per-lane row bases (clamped; OOB rows produce garbage acc, masked at store)
        int row0 = bm + wid * 32 + lm;
        int row1 = row0 + 16;
        const float* p0 = &A[(size_t)min(row0, M - 1) * 512 + lk];
        const float* p1 = &A[(size_t)min(row1, M - 1) * 512 + lk];

#pragma unroll 2
        for (int k0 = 0; k0 < 512; k0 += 32) {
            // A fragments: 8 consecutive f32 per lane -> bf16x8 via cvt_pk
            float4 q00 = *(const float4*)(p0 + k0);
            float4 q01 = *(const float4*)(p0 + k0 + 4);
            float4 q10 = *(const float4*)(p1 + k0);
            float4 q11 = *(const float4*)(p1 + k0 + 4);

            unsigned af0[4], af1[4];
            asm("v_cvt_pk_bf16_f32 %0, %1, %2" : "=v"(af0[0]) : "v"(q00.x), "v"(q00.y));
            asm("v_cvt_pk_bf16_f32 %0, %1, %2" : "=v"(af0[1]) : "v"(q00.z), "v"(q00.w));
            asm("v_cvt_pk_bf16_f32 %0, %1, %2" : "=v"(af0[2]) : "v"(q01.x), "v"(q01.y));
            asm("v_cvt_pk_bf16_f32 %0, %1, %2" : "=v"(af0[3]) : "v"(q01.z), "v"(q01.w));
            asm("v_cvt_pk_bf16_f32 %0, %1, %2" : "=v"(af1[0]) : "v"(q10.x), "v"(q10.y));
            asm("v_cvt_pk_bf16_f32 %0, %1, %2" : "=v"(af1[1]) : "v"(q10.z), "v"(q10.w));
            asm("v_cvt_pk_bf16_f32 %0, %1, %2" : "=v"(af1[2]) : "v"(q11.x), "v"(q11.y));
            asm("v_cvt_pk_bf16_f32 %0, %1, %2" : "=v"(af1[3]) : "v"(q11.z), "v"(q11.w));
            bf16x8 a0, a1;
            a0 = *(bf16x8*)af0;
            a1 = *(bf16x8*)af1;

            // B fragments: direct 16B bf16 loads from Wt (L2-hot)
            bf16x8 bf[4];
#pragma unroll
            for (int cf = 0; cf < 4; cf++)
                bf[cf] = *(const bf16x8*)&Wt[(size_t)(cf * 16 + lm) * 512 + k0 + lk];

            __builtin_amdgcn_s_setprio(1);
#pragma unroll
            for (int cf = 0; cf < 4; cf++) {
                acc[0][cf] = __builtin_amdgcn_mfma_f32_16x16x32_bf16(a0, bf[cf], acc[0][cf], 0, 0, 0);
                acc[1][cf] = __builtin_amdgcn_mfma_f32_16x16x32_bf16(a1, bf[cf], acc[1][cf], 0, 0, 0);
            }
            __builtin_amdgcn_s_setprio(0);
        }

        // epilogue: D col = lane&15, row = (lane>>4)*4 + j
#pragma unroll
        for (int rf = 0; rf < 2; rf++) {
#pragma unroll
            for (int j = 0; j < 4; j++) {
                int row = bm + wid * 32 + rf * 16 + (lane >> 4) * 4 + j;
                if (row < M) {
#pragma unroll
                    for (int cf = 0; cf < 4; cf++)
                        Hs[(size_t)row * 64 + cf * 16 + lm] = f2bf(acc[rf][cf][j]);
                }
            }
        }
    } else {
        // ---------------- bucket role ----------------
        int bi = (int)(b - g0);
        int* cnt  = smem_cnt;
        int* lcur = smem_lcur;
        const int tid = threadIdx.x;
        int e0 = bi * BCHUNK;
        int e1 = e0 + BCHUNK; if (e1 > E) e1 = E;

        for (int i = tid; i < NWIN; i += 256) cnt[i] = 0;
        __syncthreads();
        for (int e = e0 + tid; e < e1; e += 256)
            atomicAdd(&cnt[dst[e] / WIN_NODES], 1);
        __syncthreads();
        for (int i = tid; i < NWIN; i += 256)
            lcur[i] = atomicAdd(&wcur[i * WSTR], cnt[i]);
        __syncthreads();
        for (int e = e0 + tid; e < e1; e += 256) {
            int d = dst[e], s = src[e];
            int w = d / WIN_NODES;
            int pos = atomicAdd(&lcur[w], 1);
            if (pos < WCAP)
                stage[(size_t)w * WCAP + pos] =
                    ((unsigned)(d - w * WIN_NODES) << 17) | (unsigned)s;
        }
    }
}

// ---------------- csr_window: hist + scan + dinv + rowstart + fill ----------------

__global__ __launch_bounds__(256) void csr_window(
        const unsigned* __restrict__ stage,
        const int* __restrict__ wcur,
        int* __restrict__ rowstart,   // [NNODES+1]
        float* __restrict__ dinv,     // [NNODES]
        int* __restrict__ csr) {
    __shared__ int cnt[WIN_NODES];
    __shared__ int red[256];
    const int w = blockIdx.x;
    const int t = threadIdx.x;
    const int wb = w * WIN_NODES;
    const size_t sb = (size_t)w * WCAP;

    int v = (t < w) ? min(wcur[t * WSTR], WCAP) : 0;
    red[t] = v;
    __syncthreads();
#pragma unroll
    for (int off = 128; off > 0; off >>= 1) {
        if (t < off) red[t] += red[t + off];
        __syncthreads();
    }
    int woff = red[0];
    int n_w = min(wcur[w * WSTR], WCAP);
    __syncthreads();

    for (int i = t; i < WIN_NODES; i += 256) cnt[i] = 0;
    __syncthreads();
    for (int i = t; i < n_w; i += 256)
        atomicAdd(&cnt[stage[sb + i] >> 17], 1);
    __syncthreads();

    int c0 = 0, c1 = 0, c2 = 0, c3 = 0, psum = 0;
    if (t < 250) {
        c0 = cnt[4 * t]; c1 = cnt[4 * t + 1]; c2 = cnt[4 * t + 2]; c3 = cnt[4 * t + 3];
        psum = c0 + c1 + c2 + c3;
    }
    red[t] = psum;
    __syncthreads();
#pragma unroll
    for (int off = 1; off < 256; off <<= 1) {
        int tv = (t >= off) ? red[t - off] : 0;
        __syncthreads();
        red[t] += tv;
        __syncthreads();
    }
    int excl = red[t] - psum;
    if (t < 250) {
        int running = woff + excl;
        int idx = 4 * t;
        rowstart[wb + idx] = running; dinv[wb + idx] = rsqrtf((float)c0 + 1.f);
        cnt[idx] = running; running += c0;
        rowstart[wb + idx + 1] = running; dinv[wb + idx + 1] = rsqrtf((float)c1 + 1.f);
        cnt[idx + 1] = running; running += c1;
        rowstart[wb + idx + 2] = running; dinv[wb + idx + 2] = rsqrtf((float)c2 + 1.f);
        cnt[idx + 2] = running; running += c2;
        rowstart[wb + idx + 3] = running; dinv[wb + idx + 3] = rsqrtf((float)c3 + 1.f);
        cnt[idx + 3] = running;
    }
    if (w == NWIN - 1 && t == 0) rowstart[NNODES] = woff + n_w;
    __syncthreads();

    for (int i = t; i < n_w; i += 256) {
        unsigned p = stage[sb + i];
        int dl = (int)(p >> 17);
        int s  = (int)(p & 0x1FFFFu);
        int pos = atomicAdd(&cnt[dl], 1);
        csr[pos] = s;
    }
}

// ---------------- gather64 + fused 64->16 transform (per-edge dinv) ----------------

__global__ __launch_bounds__(256) void gather64_l2(
        const int* __restrict__ rowstart, const int* __restrict__ csr,
        const float* __restrict__ dinv,
        const unsigned short* __restrict__ Hs1,   // [M,64] bf16 unscaled
        const float* __restrict__ b1,
        const float* __restrict__ W2,             // [64,16]
        unsigned short* __restrict__ Hs2,         // [M,16] bf16
        int M) {
    __shared__ float Ws2[64 * 16];
    __shared__ float b1s[64];
    __shared__ float srow[8][64];
    for (int i = threadIdx.x; i < 64 * 16; i += 256) Ws2[i] = W2[i];
    if (threadIdx.x < 64) b1s[threadIdx.x] = b1[threadIdx.x];
    __syncthreads();

    const int r = threadIdx.x >> 5;
    const int lf = threadIdx.x & 31;
    const int row = blockIdx.x * 8 + r;
    const bool rok = (row < M);

    float v0 = 0.f, v1 = 0.f;
    if (rok) {
        const unsigned* H32 = (const unsigned*)Hs1;
        int e0 = rowstart[row], e1 = rowstart[row + 1];
        float dd = dinv[row];
        float acc0, acc1;
        bfpair(H32[(size_t)row * 32 + lf], acc0, acc1);
        acc0 *= dd; acc1 *= dd;
        int e = e0;
        for (; e + 3 < e1; e += 4) {
            int s0 = csr[e], s1 = csr[e + 1], s2 = csr[e + 2], s3 = csr[e + 3];
            float w0 = dinv[s0], w1 = dinv[s1], w2 = dinv[s2], w3 = dinv[s3];
            unsigned u0 = H32[(size_t)s0 * 32 + lf];
            unsigned u1 = H32[(size_t)s1 * 32 + lf];
            unsigned u2 = H32[(size_t)s2 * 32 + lf];
            unsigned u3 = H32[(size_t)s3 * 32 + lf];
            float a, b;
            bfpair(u0, a, b); acc0 += w0 * a; acc1 += w0 * b;
            bfpair(u1, a, b); acc0 += w1 * a; acc1 += w1 * b;
            bfpair(u2, a, b); acc0 += w2 * a; acc1 += w2 * b;
            bfpair(u3, a, b); acc0 += w3 * a; acc1 += w3 * b;
        }
        for (; e < e1; e++) {
            int s0 = csr[e];
            float w0 = dinv[s0];
            unsigned u = H32[(size_t)s0 * 32 + lf];
            float a, b;
            bfpair(u, a, b); acc0 += w0 * a; acc1 += w0 * b;
        }
        v0 = fmaxf(acc0 * dd + b1s[2 * lf], 0.f);
        v1 = fmaxf(acc1 * dd + b1s[2 * lf + 1], 0.f);
    }
    float2 t2; t2.x = v0; t2.y = v1;
    *(float2*)&srow[r][2 * lf] = t2;
    __syncthreads();

    if (rok && lf < 16) {
        float acc = 0.f;
#pragma unroll
        for (int k4 = 0; k4 < 16; k4++) {
            float4 s4 = *(const float4*)&srow[r][k4 * 4];
            acc += s4.x * Ws2[(k4 * 4 + 0) * 16 + lf];
            acc += s4.y * Ws2[(k4 * 4 + 1) * 16 + lf];
            acc += s4.z * Ws2[(k4 * 4 + 2) * 16 + lf];
            acc += s4.w * Ws2[(k4 * 4 + 3) * 16 + lf];
        }
        acc *= dinv[row];
        float hi = __shfl_down(acc, 1, 64);
        if ((lf & 1) == 0) {
            unsigned p = (unsigned)f2bf(acc) | ((unsigned)f2bf(hi) << 16);
            ((unsigned*)Hs2)[(size_t)row * 8 + (lf >> 1)] = p;
        }
    }
}

// ---------------- generic CSR gather (layer-2 aggregation; input pre-scaled) ----------------

template <int F, bool RELU, bool SCALEOUT, bool HASBIAS, bool OUTBF>
__global__ __launch_bounds__(256) void gather_bf(
        const int* __restrict__ rowstart,
        const int* __restrict__ csr,
        const float* __restrict__ dinv,
        const unsigned short* __restrict__ Hs,
        const float* __restrict__ bias,
        void* __restrict__ outp,
        int M) {
    constexpr int LANES = F / 2;
    constexpr int GP = 256 / LANES;
    int row = blockIdx.x * GP + threadIdx.x / LANES;
    int lf = threadIdx.x % LANES;
    if (row >= M) return;

    const unsigned* H32 = (const unsigned*)Hs;
    const size_t LP = F / 2;

    int e0 = rowstart[row], e1 = rowstart[row + 1];
    float acc0, acc1;
    bfpair(H32[(size_t)row * LP + lf], acc0, acc1);

    int e = e0;
    for (; e + 3 < e1; e += 4) {
        int s0 = csr[e], s1 = csr[e + 1], s2 = csr[e + 2], s3 = csr[e + 3];
        unsigned u0 = H32[(size_t)s0 * LP + lf];
        unsigned u1 = H32[(size_t)s1 * LP + lf];
        unsigned u2 = H32[(size_t)s2 * LP + lf];
        unsigned u3 = H32[(size_t)s3 * LP + lf];
        float a, b;
        bfpair(u0, a, b); acc0 += a; acc1 += b;
        bfpair(u1, a, b); acc0 += a; acc1 += b;
        bfpair(u2, a, b); acc0 += a; acc1 += b;
        bfpair(u3, a, b); acc0 += a; acc1 += b;
    }
    for (; e < e1; e++) {
        unsigned u = H32[(size_t)csr[e] * LP + lf];
        float a, b;
        bfpair(u, a, b); acc0 += a; acc1 += b;
    }

    float dd = dinv[row];
    float v0 = acc0 * dd, v1 = acc1 * dd;
    if (HASBIAS) { v0 += bias[2 * lf]; v1 += bias[2 * lf + 1]; }
    if (RELU) { v0 = fmaxf(v0, 0.f); v1 = fmaxf(v1, 0.f); }
    if (SCALEOUT) { v0 *= dd; v1 *= dd; }
    if (OUTBF) {
        unsigned p = (unsigned)f2bf(v0) | ((unsigned)f2bf(v1) << 16);
        ((unsigned*)outp)[(size_t)row * LP + lf] = p;
    } else {
        float2 t; t.x = v0; t.y = v1;
        ((float2*)outp)[(size_t)row * LP + lf] = t;
    }
}

// ---------------- layer-3 aggregation + 16->40 matvec + log_softmax ----------------

#define SRP 20

__global__ __launch_bounds__(256) void gather16_final(
        const int* __restrict__ rowstart, const int* __restrict__ csr,
        const float* __restrict__ dinv,
        const unsigned short* __restrict__ r2s,   // [M,16] bf16 pre-scaled
        const float* __restrict__ W3,
        const float* __restrict__ b3,
        float* __restrict__ out,
        int M) {
    __shared__ float Ws3[16 * 40];
    __shared__ float bs3[40];
    __shared__ float srow[32][SRP];
    __shared__ float orow[32 * 40];
    for (int i = threadIdx.x; i < 16 * 40; i += 256) Ws3[i] = W3[i];
    if (threadIdx.x < 40) bs3[threadIdx.x] = b3[threadIdx.x];

    const int r = threadIdx.x >> 3;
    const int lf = threadIdx.x & 7;
    const int row = blockIdx.x * 32 + r;
    const bool rok = (row < M);

    float g0 = 0.f, g1 = 0.f;
    if (rok) {
        const unsigned* H32 = (const unsigned*)r2s;
        int e0 = rowstart[row], e1 = rowstart[row + 1];
        float acc0, acc1;
        bfpair(H32[(size_t)row * 8 + lf], acc0, acc1);
        int e = e0;
        for (; e + 3 < e1; e += 4) {
            int s0 = csr[e], s1 = csr[e + 1], s2 = csr[e + 2], s3 = csr[e + 3];
            unsigned u0 = H32[(size_t)s0 * 8 + lf];
            unsigned u1 = H32[(size_t)s1 * 8 + lf];
            unsigned u2 = H32[(size_t)s2 * 8 + lf];
            unsigned u3 = H32[(size_t)s3 * 8 + lf];
            float a, b;
            bfpair(u0, a, b); acc0 += a; acc1 += b;
            bfpair(u1, a, b); acc0 += a; acc1 += b;
            bfpair(u2, a, b); acc0 += a; acc1 += b;
            bfpair(u3, a, b); acc0 += a; acc1 += b;
        }
        for (; e < e1; e++) {
            unsigned u = H32[(size_t)csr[e] * 8 + lf];
            float a, b;
            bfpair(u, a, b); acc0 += a; acc1 += b;
        }
        float dd = dinv[row];
        g0 = acc0 * dd; g1 = acc1 * dd;
    }
    float2 t2; t2.x = g0; t2.y = g1;
    *(float2*)&srow[r][2 * lf] = t2;
    __syncthreads();

    float vals[5];
#pragma unroll
    for (int q = 0; q < 5; q++) vals[q] = bs3[lf + 8 * q];
#pragma unroll
    for (int k4 = 0; k4 < 4; k4++) {
        float4 s4 = *(const float4*)&srow[r][k4 * 4];
#pragma unroll
        for (int q = 0; q < 5; q++) {
            int n = lf + 8 * q;
            vals[q] += s4.x * Ws3[(k4 * 4 + 0) * 40 + n];
            vals[q] += s4.y * Ws3[(k4 * 4 + 1) * 40 + n];
            vals[q] += s4.z * Ws3[(k4 * 4 + 2) * 40 + n];
            vals[q] += s4.w * Ws3[(k4 * 4 + 3) * 40 + n];
        }
    }
    float m = vals[0];
#pragma unroll
    for (int q = 1; q < 5; q++) m = fmaxf(m, vals[q]);
#pragma unroll
    for (int off = 1; off < 8; off <<= 1) m = fmaxf(m, __shfl_xor(m, off, 64));
    float s = 0.f;
#pragma unroll
    for (int q = 0; q < 5; q++) s += expf(vals[q] - m);
#pragma unroll
    for (int off = 1; off < 8; off <<= 1) s += __shfl_xor(s, off, 64);
    float ls = logf(s) + m;
#pragma unroll
    for (int q = 0; q < 5; q++) orow[r * 40 + lf + 8 * q] = vals[q] - ls;
    __syncthreads();

    float4* o4 = (float4*)(out + (size_t)blockIdx.x * 32 * 40);
    const float4* s4p = (const float4*)orow;
    for (int i = threadIdx.x; i < 320; i += 256) {
        int rr = (i * 4) / 40;
        if (blockIdx.x * 32 + rr < M) o4[i] = s4p[i];
    }
}

// ---------------- launch ----------------

extern "C" void kernel_launch(void* const* d_in, const int* in_sizes, int n_in,
                              void* d_out, int out_size, void* d_ws, size_t ws_size,
                              hipStream_t stream) {
    const float* x   = (const float*)d_in[0];
    const int*   ei  = (const int*)d_in[1];
    const int*   src = ei;
    const int*   dst = ei + NEDGES;
    const float* W1 = (const float*)d_in[2];
    const float* b1 = (const float*)d_in[3];
    const float* W2 = (const float*)d_in[4];
    const float* b2 = (const float*)d_in[5];
    const float* W3 = (const float*)d_in[6];
    const float* b3 = (const float*)d_in[7];
    float* out = (float*)d_out;

    int* ws_i = (int*)d_ws;
    int* wcur     = ws_i;                        // NWIN*WSTR
    int* rowstart = wcur + NWIN * WSTR + 16;     // N+8
    int* csr      = rowstart + NNODES + 8;       // E
    unsigned* stage = (unsigned*)(csr + NEDGES); // NWIN*WCAP
    float* dinv   = (float*)(stage + (size_t)NWIN * WCAP);  // N
    unsigned short* Wt = (unsigned short*)(dinv + NNODES);  // 64*512 bf16
    float* bufA   = (float*)((int*)(Wt + 64 * 512) + 16);
    float* bufB   = bufA + (size_t)NNODES * 64;

    unsigned short* Hs1 = (unsigned short*)bufA;   // [N,64] bf16 unscaled
    unsigned short* Hs2 = (unsigned short*)bufB;   // [N,16] bf16
    unsigned short* r2s = (unsigned short*)bufA;   // [N,16] bf16 (Hs1 dead)

    // --- W1 -> bf16^T + wcur zero ---
    convW<<<128, 256, 0, stream>>>(W1, Wt, wcur);

    // --- MEGA: LDS-free GEMM (x@W1, unscaled) overlapped with edge bucketing ---
    mega_gemm_bucket<<<MEGA_BLOCKS, 256, 0, stream>>>(
        x, Wt, Hs1, src, dst, stage, wcur, NNODES, NEDGES);

    // --- CSR finalize: one block per window ---
    csr_window<<<NWIN, 256, 0, stream>>>(stage, wcur, rowstart, dinv, csr);

    // --- layer-1 aggregation (per-edge dinv) + fused 64->16 transform ---
    gather64_l2<<<(NNODES + 7) / 8, 256, 0, stream>>>(
        rowstart, csr, dinv, Hs1, b1, W2, Hs2, NNODES);

    // --- layer-2 aggregation (relu + b2 + pre-scale) ---
    gather_bf<16, true, true, true, true><<<(NNODES + 31) / 32, 256, 0, stream>>>(
        rowstart, csr, dinv, Hs2, b2, r2s, NNODES);

    // --- layer-3 aggregation + 16->40 matvec + log_softmax ---
    gather16_final<<<(NNODES + 31) / 32, 256, 0, stream>>>(
        rowstart, csr, dinv, r2s, W3, b3, out, NNODES);
}

// Round 13
// 231.540 us; speedup vs baseline: 2.2710x; 1.0103x over previous
//
#include <hip/hip_runtime.h>
#include <cstdint>
#include <cstddef>

#define NNODES 100000
#define NEDGES 1600000
#define NWIN 100
#define WIN_NODES 1000
#define WCAP 17408
#define WSTR 16

#define GM_ROWS 128
#define APAD 72
#define GEMM_BLOCKS ((NNODES + GM_ROWS - 1) / GM_ROWS)   // 782
#define BUCKET_BLOCKS 512
#define BCHUNK ((NEDGES + BUCKET_BLOCKS - 1) / BUCKET_BLOCKS)  // 3125
#define MEGA_BLOCKS (GEMM_BLOCKS + BUCKET_BLOCKS)        // 1294

typedef __attribute__((ext_vector_type(8))) short bf16x8;
typedef __attribute__((ext_vector_type(4))) float f32x4;

__device__ inline unsigned short f2bf(float f) {
    union { float f; unsigned u; } v; v.f = f;
    unsigned r = v.u + 0x7FFFu + ((v.u >> 16) & 1u);   // RNE
    return (unsigned short)(r >> 16);
}
__device__ inline void bfpair(unsigned u, float& lo, float& hi) {
    union { unsigned x; float f; } a, b;
    a.x = u << 16; b.x = u & 0xffff0000u;
    lo = a.f; hi = b.f;
}

// ---------------- W1 convert+transpose (+ wcur zero) ----------------

__global__ __launch_bounds__(256) void convW(const float* __restrict__ W,
                                             unsigned short* __restrict__ Wt,
                                             int* __restrict__ wcur) {
    if (blockIdx.x == 0 && threadIdx.x < NWIN) wcur[threadIdx.x * WSTR] = 0;
    int i = blockIdx.x * 256 + threadIdx.x;
    if (i < 512 * 64) {
        int k = i >> 6, n = i & 63;
        Wt[n * 512 + k] = f2bf(W[i]);
    }
}

// ---------------- MEGA kernel: barrier-free GEMM role + edge-bucketing role ----------------
// GEMM role: each wave owns 32 rows and stages them into its OWN LDS slice.
// Global A-loads fully coalesced (16 lanes x float4 = one row's 64-k segment);
// fragment ds_reads hit only this wave's slice -> NO __syncthreads at all.
// Intra-wave ds ordering = compiler lgkmcnt. B direct from L2-hot bf16 Wt.

__global__ __launch_bounds__(256) void mega_gemm_bucket(
        const float* __restrict__ A,            // [M,512] x
        const unsigned short* __restrict__ Wt,  // [64][512] bf16
        unsigned short* __restrict__ Hs,        // [M,64] bf16 UNSCALED out
        const int* __restrict__ src, const int* __restrict__ dst,
        unsigned* __restrict__ stage,
        int* __restrict__ wcur, int M, int E) {
    __shared__ __align__(16) unsigned char smem[4 * 32 * APAD * 2];  // 18432B

    long long b = blockIdx.x;
    int g0 = (int)((b * GEMM_BLOCKS) / MEGA_BLOCKS);
    int g1 = (int)(((b + 1) * GEMM_BLOCKS) / MEGA_BLOCKS);

    if (g1 > g0) {
        // ---------------- GEMM role (wave-private staging, barrier-free) ----------------
        typedef unsigned short Slice[32][APAD];
        Slice* As = (Slice*)smem;               // [4][32][72]
        const int tid = threadIdx.x;
        const int wv = tid >> 6;
        const int lane = tid & 63;
        const int lm = lane & 15;
        const int lk = (lane >> 4) * 8;
        const int lr4 = lane >> 4;              // staging row-in-group 0..3
        const int lc4 = lane & 15;              // staging float4 col
        const int bm = g0 * GM_ROWS + wv * 32;  // wave's 32-row base

        f32x4 acc[2][4];
#pragma unroll
        for (int i = 0; i < 2; i++)
#pragma unroll
            for (int j = 0; j < 4; j++) acc[i][j] = (f32x4){0.f, 0.f, 0.f, 0.f};

        for (int k0 = 0; k0 < 512; k0 += 64) {
            // stage this wave's 32 rows x 64 k (coalesced; f32->bf16 via cvt_pk)
#pragma unroll
            for (int p = 0; p < 8; p++) {
                int rl = p * 4 + lr4;
                int row = bm + rl;
                float4 v;
                if (row < M) v = *(const float4*)&A[(size_t)row * 512 + k0 + lc4 * 4];
                else         v = make_float4(0.f, 0.f, 0.f, 0.f);
                unsigned lo, hi;
                asm("v_cvt_pk_bf16_f32 %0, %1, %2" : "=v"(lo) : "v"(v.x), "v"(v.y));
                asm("v_cvt_pk_bf16_f32 %0, %1, %2" : "=v"(hi) : "v"(v.z), "v"(v.w));
                uint2 u; u.x = lo; u.y = hi;
                *(uint2*)&As[wv][rl][lc4 * 4] = u;
            }
            // fragments from own slice (lgkmcnt ordering, no barrier)
            bf16x8 af[2][2];
#pragma unroll
            for (int rf = 0; rf < 2; rf++)
#pragma unroll
                for (int kf = 0; kf < 2; kf++)
                    af[rf][kf] = *(const bf16x8*)&As[wv][rf * 16 + lm][kf * 32 + lk];
            // B fragments direct from L2-hot Wt
            bf16x8 bf[4][2];
#pragma unroll
            for (int cf = 0; cf < 4; cf++)
#pragma unroll
                for (int kf = 0; kf < 2; kf++)
                    bf[cf][kf] = *(const bf16x8*)&Wt[(size_t)(cf * 16 + lm) * 512 + k0 + kf * 32 + lk];

            __builtin_amdgcn_s_setprio(1);
#pragma unroll
            for (int kf = 0; kf < 2; kf++)
#pragma unroll
                for (int rf = 0; rf < 2; rf++)
#pragma unroll
                    for (int cf = 0; cf < 4; cf++)
                        acc[rf][cf] = __builtin_amdgcn_mfma_f32_16x16x32_bf16(
                            af[rf][kf], bf[cf][kf], acc[rf][cf], 0, 0, 0);
            __builtin_amdgcn_s_setprio(0);
        }

        // epilogue: D col = lane&15, row = (lane>>4)*4 + j
#pragma unroll
        for (int rf = 0; rf < 2; rf++) {
#pragma unroll
            for (int j = 0; j < 4; j++) {
                int row = bm + rf * 16 + (lane >> 4) * 4 + j;
                if (row < M) {
#pragma unroll
                    for (int cf = 0; cf < 4; cf++)
                        Hs[(size_t)row * 64 + cf * 16 + lm] = f2bf(acc[rf][cf][j]);
                }
            }
        }
    } else {
        // ---------------- bucket role ----------------
        int bi = (int)(b - g0);
        int* cnt  = (int*)smem;         // NWIN
        int* lcur = cnt + NWIN;         // NWIN
        const int tid = threadIdx.x;
        int e0 = bi * BCHUNK;
        int e1 = e0 + BCHUNK; if (e1 > E) e1 = E;

        for (int i = tid; i < NWIN; i += 256) cnt[i] = 0;
        __syncthreads();
        for (int e = e0 + tid; e < e1; e += 256)
            atomicAdd(&cnt[dst[e] / WIN_NODES], 1);
        __syncthreads();
        for (int i = tid; i < NWIN; i += 256)
            lcur[i] = atomicAdd(&wcur[i * WSTR], cnt[i]);
        __syncthreads();
        for (int e = e0 + tid; e < e1; e += 256) {
            int d = dst[e], s = src[e];
            int w = d / WIN_NODES;
            int pos = atomicAdd(&lcur[w], 1);
            if (pos < WCAP)
                stage[(size_t)w * WCAP + pos] =
                    ((unsigned)(d - w * WIN_NODES) << 17) | (unsigned)s;
        }
    }
}

// ---------------- csr_window: hist + scan + dinv + rowstart + fill ----------------

__global__ __launch_bounds__(256) void csr_window(
        const unsigned* __restrict__ stage,
        const int* __restrict__ wcur,
        int* __restrict__ rowstart,   // [NNODES+1]
        float* __restrict__ dinv,     // [NNODES]
        int* __restrict__ csr) {
    __shared__ int cnt[WIN_NODES];
    __shared__ int red[256];
    const int w = blockIdx.x;
    const int t = threadIdx.x;
    const int wb = w * WIN_NODES;
    const size_t sb = (size_t)w * WCAP;

    int v = (t < w) ? min(wcur[t * WSTR], WCAP) : 0;
    red[t] = v;
    __syncthreads();
#pragma unroll
    for (int off = 128; off > 0; off >>= 1) {
        if (t < off) red[t] += red[t + off];
        __syncthreads();
    }
    int woff = red[0];
    int n_w = min(wcur[w * WSTR], WCAP);
    __syncthreads();

    for (int i = t; i < WIN_NODES; i += 256) cnt[i] = 0;
    __syncthreads();
    for (int i = t; i < n_w; i += 256)
        atomicAdd(&cnt[stage[sb + i] >> 17], 1);
    __syncthreads();

    int c0 = 0, c1 = 0, c2 = 0, c3 = 0, psum = 0;
    if (t < 250) {
        c0 = cnt[4 * t]; c1 = cnt[4 * t + 1]; c2 = cnt[4 * t + 2]; c3 = cnt[4 * t + 3];
        psum = c0 + c1 + c2 + c3;
    }
    red[t] = psum;
    __syncthreads();
#pragma unroll
    for (int off = 1; off < 256; off <<= 1) {
        int tv = (t >= off) ? red[t - off] : 0;
        __syncthreads();
        red[t] += tv;
        __syncthreads();
    }
    int excl = red[t] - psum;
    if (t < 250) {
        int running = woff + excl;
        int idx = 4 * t;
        rowstart[wb + idx] = running; dinv[wb + idx] = rsqrtf((float)c0 + 1.f);
        cnt[idx] = running; running += c0;
        rowstart[wb + idx + 1] = running; dinv[wb + idx + 1] = rsqrtf((float)c1 + 1.f);
        cnt[idx + 1] = running; running += c1;
        rowstart[wb + idx + 2] = running; dinv[wb + idx + 2] = rsqrtf((float)c2 + 1.f);
        cnt[idx + 2] = running; running += c2;
        rowstart[wb + idx + 3] = running; dinv[wb + idx + 3] = rsqrtf((float)c3 + 1.f);
        cnt[idx + 3] = running;
    }
    if (w == NWIN - 1 && t == 0) rowstart[NNODES] = woff + n_w;
    __syncthreads();

    for (int i = t; i < n_w; i += 256) {
        unsigned p = stage[sb + i];
        int dl = (int)(p >> 17);
        int s  = (int)(p & 0x1FFFFu);
        int pos = atomicAdd(&cnt[dl], 1);
        csr[pos] = s;
    }
}

// ---------------- gather64 + fused 64->16 transform (per-edge dinv) ----------------

__global__ __launch_bounds__(256) void gather64_l2(
        const int* __restrict__ rowstart, const int* __restrict__ csr,
        const float* __restrict__ dinv,
        const unsigned short* __restrict__ Hs1,   // [M,64] bf16 unscaled
        const float* __restrict__ b1,
        const float* __restrict__ W2,             // [64,16]
        unsigned short* __restrict__ Hs2,         // [M,16] bf16
        int M) {
    __shared__ float Ws2[64 * 16];
    __shared__ float b1s[64];
    __shared__ float srow[8][64];
    for (int i = threadIdx.x; i < 64 * 16; i += 256) Ws2[i] = W2[i];
    if (threadIdx.x < 64) b1s[threadIdx.x] = b1[threadIdx.x];
    __syncthreads();

    const int r = threadIdx.x >> 5;
    const int lf = threadIdx.x & 31;
    const int row = blockIdx.x * 8 + r;
    const bool rok = (row < M);

    float v0 = 0.f, v1 = 0.f;
    if (rok) {
        const unsigned* H32 = (const unsigned*)Hs1;
        int e0 = rowstart[row], e1 = rowstart[row + 1];
        float dd = dinv[row];
        float acc0, acc1;
        bfpair(H32[(size_t)row * 32 + lf], acc0, acc1);
        acc0 *= dd; acc1 *= dd;
        int e = e0;
        for (; e + 3 < e1; e += 4) {
            int s0 = csr[e], s1 = csr[e + 1], s2 = csr[e + 2], s3 = csr[e + 3];
            float w0 = dinv[s0], w1 = dinv[s1], w2 = dinv[s2], w3 = dinv[s3];
            unsigned u0 = H32[(size_t)s0 * 32 + lf];
            unsigned u1 = H32[(size_t)s1 * 32 + lf];
            unsigned u2 = H32[(size_t)s2 * 32 + lf];
            unsigned u3 = H32[(size_t)s3 * 32 + lf];
            float a, b;
            bfpair(u0, a, b); acc0 += w0 * a; acc1 += w0 * b;
            bfpair(u1, a, b); acc0 += w1 * a; acc1 += w1 * b;
            bfpair(u2, a, b); acc0 += w2 * a; acc1 += w2 * b;
            bfpair(u3, a, b); acc0 += w3 * a; acc1 += w3 * b;
        }
        for (; e < e1; e++) {
            int s0 = csr[e];
            float w0 = dinv[s0];
            unsigned u = H32[(size_t)s0 * 32 + lf];
            float a, b;
            bfpair(u, a, b); acc0 += w0 * a; acc1 += w0 * b;
        }
        v0 = fmaxf(acc0 * dd + b1s[2 * lf], 0.f);
        v1 = fmaxf(acc1 * dd + b1s[2 * lf + 1], 0.f);
    }
    float2 t2; t2.x = v0; t2.y = v1;
    *(float2*)&srow[r][2 * lf] = t2;
    __syncthreads();

    if (rok && lf < 16) {
        float acc = 0.f;
#pragma unroll
        for (int k4 = 0; k4 < 16; k4++) {
            float4 s4 = *(const float4*)&srow[r][k4 * 4];
            acc += s4.x * Ws2[(k4 * 4 + 0) * 16 + lf];
            acc += s4.y * Ws2[(k4 * 4 + 1) * 16 + lf];
            acc += s4.z * Ws2[(k4 * 4 + 2) * 16 + lf];
            acc += s4.w * Ws2[(k4 * 4 + 3) * 16 + lf];
        }
        acc *= dinv[row];
        float hi = __shfl_down(acc, 1, 64);
        if ((lf & 1) == 0) {
            unsigned p = (unsigned)f2bf(acc) | ((unsigned)f2bf(hi) << 16);
            ((unsigned*)Hs2)[(size_t)row * 8 + (lf >> 1)] = p;
        }
    }
}

// ---------------- generic CSR gather (layer-2 aggregation; input pre-scaled) ----------------

template <int F, bool RELU, bool SCALEOUT, bool HASBIAS, bool OUTBF>
__global__ __launch_bounds__(256) void gather_bf(
        const int* __restrict__ rowstart,
        const int* __restrict__ csr,
        const float* __restrict__ dinv,
        const unsigned short* __restrict__ Hs,
        const float* __restrict__ bias,
        void* __restrict__ outp,
        int M) {
    constexpr int LANES = F / 2;
    constexpr int GP = 256 / LANES;
    int row = blockIdx.x * GP + threadIdx.x / LANES;
    int lf = threadIdx.x % LANES;
    if (row >= M) return;

    const unsigned* H32 = (const unsigned*)Hs;
    const size_t LP = F / 2;

    int e0 = rowstart[row], e1 = rowstart[row + 1];
    float acc0, acc1;
    bfpair(H32[(size_t)row * LP + lf], acc0, acc1);

    int e = e0;
    for (; e + 3 < e1; e += 4) {
        int s0 = csr[e], s1 = csr[e + 1], s2 = csr[e + 2], s3 = csr[e + 3];
        unsigned u0 = H32[(size_t)s0 * LP + lf];
        unsigned u1 = H32[(size_t)s1 * LP + lf];
        unsigned u2 = H32[(size_t)s2 * LP + lf];
        unsigned u3 = H32[(size_t)s3 * LP + lf];
        float a, b;
        bfpair(u0, a, b); acc0 += a; acc1 += b;
        bfpair(u1, a, b); acc0 += a; acc1 += b;
        bfpair(u2, a, b); acc0 += a; acc1 += b;
        bfpair(u3, a, b); acc0 += a; acc1 += b;
    }
    for (; e < e1; e++) {
        unsigned u = H32[(size_t)csr[e] * LP + lf];
        float a, b;
        bfpair(u, a, b); acc0 += a; acc1 += b;
    }

    float dd = dinv[row];
    float v0 = acc0 * dd, v1 = acc1 * dd;
    if (HASBIAS) { v0 += bias[2 * lf]; v1 += bias[2 * lf + 1]; }
    if (RELU) { v0 = fmaxf(v0, 0.f); v1 = fmaxf(v1, 0.f); }
    if (SCALEOUT) { v0 *= dd; v1 *= dd; }
    if (OUTBF) {
        unsigned p = (unsigned)f2bf(v0) | ((unsigned)f2bf(v1) << 16);
        ((unsigned*)outp)[(size_t)row * LP + lf] = p;
    } else {
        float2 t; t.x = v0; t.y = v1;
        ((float2*)outp)[(size_t)row * LP + lf] = t;
    }
}

// ---------------- layer-3 aggregation + 16->40 matvec + log_softmax ----------------

#define SRP 20

__global__ __launch_bounds__(256) void gather16_final(
        const int* __restrict__ rowstart, const int* __restrict__ csr,
        const float* __restrict__ dinv,
        const unsigned short* __restrict__ r2s,   // [M,16] bf16 pre-scaled
        const float* __restrict__ W3,
        const float* __restrict__ b3,
        float* __restrict__ out,
        int M) {
    __shared__ float Ws3[16 * 40];
    __shared__ float bs3[40];
    __shared__ float srow[32][SRP];
    __shared__ float orow[32 * 40];
    for (int i = threadIdx.x; i < 16 * 40; i += 256) Ws3[i] = W3[i];
    if (threadIdx.x < 40) bs3[threadIdx.x] = b3[threadIdx.x];

    const int r = threadIdx.x >> 3;
    const int lf = threadIdx.x & 7;
    const int row = blockIdx.x * 32 + r;
    const bool rok = (row < M);

    float g0 = 0.f, g1 = 0.f;
    if (rok) {
        const unsigned* H32 = (const unsigned*)r2s;
        int e0 = rowstart[row], e1 = rowstart[row + 1];
        float acc0, acc1;
        bfpair(H32[(size_t)row * 8 + lf], acc0, acc1);
        int e = e0;
        for (; e + 3 < e1; e += 4) {
            int s0 = csr[e], s1 = csr[e + 1], s2 = csr[e + 2], s3 = csr[e + 3];
            unsigned u0 = H32[(size_t)s0 * 8 + lf];
            unsigned u1 = H32[(size_t)s1 * 8 + lf];
            unsigned u2 = H32[(size_t)s2 * 8 + lf];
            unsigned u3 = H32[(size_t)s3 * 8 + lf];
            float a, b;
            bfpair(u0, a, b); acc0 += a; acc1 += b;
            bfpair(u1, a, b); acc0 += a; acc1 += b;
            bfpair(u2, a, b); acc0 += a; acc1 += b;
            bfpair(u3, a, b); acc0 += a; acc1 += b;
        }
        for (; e < e1; e++) {
            unsigned u = H32[(size_t)csr[e] * 8 + lf];
            float a, b;
            bfpair(u, a, b); acc0 += a; acc1 += b;
        }
        float dd = dinv[row];
        g0 = acc0 * dd; g1 = acc1 * dd;
    }
    float2 t2; t2.x = g0; t2.y = g1;
    *(float2*)&srow[r][2 * lf] = t2;
    __syncthreads();

    float vals[5];
#pragma unroll
    for (int q = 0; q < 5; q++) vals[q] = bs3[lf + 8 * q];
#pragma unroll
    for (int k4 = 0; k4 < 4; k4++) {
        float4 s4 = *(const float4*)&srow[r][k4 * 4];
#pragma unroll
        for (int q = 0; q < 5; q++) {
            int n = lf + 8 * q;
            vals[q] += s4.x * Ws3[(k4 * 4 + 0) * 40 + n];
            vals[q] += s4.y * Ws3[(k4 * 4 + 1) * 40 + n];
            vals[q] += s4.z * Ws3[(k4 * 4 + 2) * 40 + n];
            vals[q] += s4.w * Ws3[(k4 * 4 + 3) * 40 + n];
        }
    }
    float m = vals[0];
#pragma unroll
    for (int q = 1; q < 5; q++) m = fmaxf(m, vals[q]);
#pragma unroll
    for (int off = 1; off < 8; off <<= 1) m = fmaxf(m, __shfl_xor(m, off, 64));
    float s = 0.f;
#pragma unroll
    for (int q = 0; q < 5; q++) s += expf(vals[q] - m);
#pragma unroll
    for (int off = 1; off < 8; off <<= 1) s += __shfl_xor(s, off, 64);
    float ls = logf(s) + m;
#pragma unroll
    for (int q = 0; q < 5; q++) orow[r * 40 + lf + 8 * q] = vals[q] - ls;
    __syncthreads();

    float4* o4 = (float4*)(out + (size_t)blockIdx.x * 32 * 40);
    const float4* s4p = (const float4*)orow;
    for (int i = threadIdx.x; i < 320; i += 256) {
        int rr = (i * 4) / 40;
        if (blockIdx.x * 32 + rr < M) o4[i] = s4p[i];
    }
}

// ---------------- launch ----------------

extern "C" void kernel_launch(void* const* d_in, const int* in_sizes, int n_in,
                              void* d_out, int out_size, void* d_ws, size_t ws_size,
                              hipStream_t stream) {
    const float* x   = (const float*)d_in[0];
    const int*   ei  = (const int*)d_in[1];
    const int*   src = ei;
    const int*   dst = ei + NEDGES;
    const float* W1 = (const float*)d_in[2];
    const float* b1 = (const float*)d_in[3];
    const float* W2 = (const float*)d_in[4];
    const float* b2 = (const float*)d_in[5];
    const float* W3 = (const float*)d_in[6];
    const float* b3 = (const float*)d_in[7];
    float* out = (float*)d_out;

    int* ws_i = (int*)d_ws;
    int* wcur     = ws_i;                        // NWIN*WSTR
    int* rowstart = wcur + NWIN * WSTR + 16;     // N+8
    int* csr      = rowstart + NNODES + 8;       // E
    unsigned* stage = (unsigned*)(csr + NEDGES); // NWIN*WCAP
    float* dinv   = (float*)(stage + (size_t)NWIN * WCAP);  // N
    unsigned short* Wt = (unsigned short*)(dinv + NNODES);  // 64*512 bf16
    float* bufA   = (float*)((int*)(Wt + 64 * 512) + 16);
    float* bufB   = bufA + (size_t)NNODES * 64;

    unsigned short* Hs1 = (unsigned short*)bufA;   // [N,64] bf16 unscaled
    unsigned short* Hs2 = (unsigned short*)bufB;   // [N,16] bf16
    unsigned short* r2s = (unsigned short*)bufA;   // [N,16] bf16 (Hs1 dead)

    // --- W1 -> bf16^T + wcur zero ---
    convW<<<128, 256, 0, stream>>>(W1, Wt, wcur);

    // --- MEGA: barrier-free GEMM (x@W1, unscaled) overlapped with edge bucketing ---
    mega_gemm_bucket<<<MEGA_BLOCKS, 256, 0, stream>>>(
        x, Wt, Hs1, src, dst, stage, wcur, NNODES, NEDGES);

    // --- CSR finalize: one block per window ---
    csr_window<<<NWIN, 256, 0, stream>>>(stage, wcur, rowstart, dinv, csr);

    // --- layer-1 aggregation (per-edge dinv) + fused 64->16 transform ---
    gather64_l2<<<(NNODES + 7) / 8, 256, 0, stream>>>(
        rowstart, csr, dinv, Hs1, b1, W2, Hs2, NNODES);

    // --- layer-2 aggregation (relu + b2 + pre-scale) ---
    gather_bf<16, true, true, true, true><<<(NNODES + 31) / 32, 256, 0, stream>>>(
        rowstart, csr, dinv, Hs2, b2, r2s, NNODES);

    // --- layer-3 aggregation + 16->40 matvec + log_softmax ---
    gather16_final<<<(NNODES + 31) / 32, 256, 0, stream>>>(
        rowstart, csr, dinv, r2s, W3, b3, out, NNODES);
}

// Round 14
// 216.081 us; speedup vs baseline: 2.4335x; 1.0715x over previous
//
#include <hip/hip_runtime.h>
#include <cstdint>
#include <cstddef>

#define NNODES 100000
#define NEDGES 1600000
#define NWIN 100
#define WIN_NODES 1000
#define WCAP 17408
#define WSTR 16

#define GM_ROWS 128
#define APAD 72
#define GEMM_BLOCKS ((NNODES + GM_ROWS - 1) / GM_ROWS)   // 782
#define BUCKET_BLOCKS 512
#define BCHUNK ((NEDGES + BUCKET_BLOCKS - 1) / BUCKET_BLOCKS)  // 3125

typedef __attribute__((ext_vector_type(8))) short bf16x8;
typedef __attribute__((ext_vector_type(4))) float f32x4;
typedef __attribute__((ext_vector_type(8))) unsigned short ushort8v;

__device__ inline unsigned short f2bf(float f) {
    union { float f; unsigned u; } v; v.f = f;
    unsigned r = v.u + 0x7FFFu + ((v.u >> 16) & 1u);   // RNE
    return (unsigned short)(r >> 16);
}
__device__ inline void bfpair(unsigned u, float& lo, float& hi) {
    union { unsigned x; float f; } a, b;
    a.x = u << 16; b.x = u & 0xffff0000u;
    lo = a.f; hi = b.f;
}

// ---------------- W1 convert+transpose (+ wcur zero) ----------------

__global__ __launch_bounds__(256) void convW(const float* __restrict__ W,
                                             unsigned short* __restrict__ Wt,
                                             int* __restrict__ wcur) {
    if (blockIdx.x == 0 && threadIdx.x < NWIN) wcur[threadIdx.x * WSTR] = 0;
    int i = blockIdx.x * 256 + threadIdx.x;
    if (i < 512 * 64) {
        int k = i >> 6, n = i & 63;
        Wt[n * 512 + k] = f2bf(W[i]);
    }
}

// ---------------- gemm_k: standalone GEMM (r9 structure: LDS-staged, 2-deep prefetch) ----------------

__global__ __launch_bounds__(256) void gemm_k(
        const float* __restrict__ A,            // [M,512] x
        const unsigned short* __restrict__ Wt,  // [64][512] bf16
        unsigned short* __restrict__ Hs,        // [M,64] bf16 UNSCALED out
        int M) {
    __shared__ __align__(16) unsigned char smem[18432 + 9216];
    typedef unsigned short RowA[APAD];
    RowA* As = (RowA*)smem;
    RowA* Bs = (RowA*)(smem + 18432);
    const int tid = threadIdx.x;
    const int wid = tid >> 6;
    const int lane = tid & 63;
    const int bm = blockIdx.x * GM_ROWS;

    f32x4 acc[2][4];
#pragma unroll
    for (int i = 0; i < 2; i++)
#pragma unroll
        for (int j = 0; j < 4; j++) acc[i][j] = (f32x4){0.f, 0.f, 0.f, 0.f};

    const int ar = tid >> 4;
    const int ac4 = tid & 15;
    const int lm = lane & 15;
    const int lk = (lane >> 4) * 8;

    float4 aR0[8], aR1[8];
    ushort8v bR0[2], bR1[2];

    auto LOADA = [&](float4 (&aRx)[8], ushort8v (&bRx)[2], int k0) {
#pragma unroll
        for (int p = 0; p < 8; p++) {
            int row = bm + p * 16 + ar;
            if (row < M) aRx[p] = *(const float4*)&A[(size_t)row * 512 + k0 + ac4 * 4];
            else         aRx[p] = make_float4(0.f, 0.f, 0.f, 0.f);
        }
#pragma unroll
        for (int p = 0; p < 2; p++) {
            int c = p * 256 + tid;
            int n = c >> 3, kc = c & 7;
            bRx[p] = *(const ushort8v*)&Wt[(size_t)n * 512 + k0 + kc * 8];
        }
    };

    auto TILE = [&](float4 (&aRx)[8], ushort8v (&bRx)[2], int k0) {
#pragma unroll
        for (int p = 0; p < 8; p++) {
            int r = p * 16 + ar;
            unsigned lo, hi;
            asm("v_cvt_pk_bf16_f32 %0, %1, %2" : "=v"(lo) : "v"(aRx[p].x), "v"(aRx[p].y));
            asm("v_cvt_pk_bf16_f32 %0, %1, %2" : "=v"(hi) : "v"(aRx[p].z), "v"(aRx[p].w));
            uint2 u; u.x = lo; u.y = hi;
            *(uint2*)&As[r][ac4 * 4] = u;
        }
#pragma unroll
        for (int p = 0; p < 2; p++) {
            int c = p * 256 + tid;
            int n = c >> 3, kc = c & 7;
            *(ushort8v*)&Bs[n][kc * 8] = bRx[p];
        }
        __syncthreads();

        if (k0 + 128 < 512) LOADA(aRx, bRx, k0 + 128);   // 2-tile-ahead prefetch

        bf16x8 a[2][2], bb[4][2];
#pragma unroll
        for (int rf = 0; rf < 2; rf++)
#pragma unroll
            for (int kf = 0; kf < 2; kf++)
                a[rf][kf] = *(const bf16x8*)&As[wid * 32 + rf * 16 + lm][kf * 32 + lk];
#pragma unroll
        for (int cf = 0; cf < 4; cf++)
#pragma unroll
            for (int kf = 0; kf < 2; kf++)
                bb[cf][kf] = *(const bf16x8*)&Bs[cf * 16 + lm][kf * 32 + lk];

        __builtin_amdgcn_s_setprio(1);
#pragma unroll
        for (int kf = 0; kf < 2; kf++)
#pragma unroll
            for (int rf = 0; rf < 2; rf++)
#pragma unroll
                for (int cf = 0; cf < 4; cf++)
                    acc[rf][cf] = __builtin_amdgcn_mfma_f32_16x16x32_bf16(
                        a[rf][kf], bb[cf][kf], acc[rf][cf], 0, 0, 0);
        __builtin_amdgcn_s_setprio(0);
        __syncthreads();
    };

    LOADA(aR0, bR0, 0);
    LOADA(aR1, bR1, 64);
    for (int tp = 0; tp < 4; tp++) {
        TILE(aR0, bR0, tp * 128);
        TILE(aR1, bR1, tp * 128 + 64);
    }

#pragma unroll
    for (int rf = 0; rf < 2; rf++) {
#pragma unroll
        for (int j = 0; j < 4; j++) {
            int row = bm + wid * 32 + rf * 16 + (lane >> 4) * 4 + j;
            if (row < M) {
#pragma unroll
                for (int cf = 0; cf < 4; cf++)
                    Hs[(size_t)row * 64 + cf * 16 + lm] = f2bf(acc[rf][cf][j]);
            }
        }
    }
}

// ---------------- bucket_k: standalone edge bucketing ----------------

__global__ __launch_bounds__(256) void bucket_k(
        const int* __restrict__ src, const int* __restrict__ dst,
        unsigned* __restrict__ stage,
        int* __restrict__ wcur, int E) {
    __shared__ int cnt[NWIN];
    __shared__ int lcur[NWIN];
    const int tid = threadIdx.x;
    int e0 = blockIdx.x * BCHUNK;
    int e1 = e0 + BCHUNK; if (e1 > E) e1 = E;

    for (int i = tid; i < NWIN; i += 256) cnt[i] = 0;
    __syncthreads();
    for (int e = e0 + tid; e < e1; e += 256)
        atomicAdd(&cnt[dst[e] / WIN_NODES], 1);
    __syncthreads();
    for (int i = tid; i < NWIN; i += 256)
        lcur[i] = atomicAdd(&wcur[i * WSTR], cnt[i]);
    __syncthreads();
    for (int e = e0 + tid; e < e1; e += 256) {
        int d = dst[e], s = src[e];
        int w = d / WIN_NODES;
        int pos = atomicAdd(&lcur[w], 1);
        if (pos < WCAP)
            stage[(size_t)w * WCAP + pos] =
                ((unsigned)(d - w * WIN_NODES) << 17) | (unsigned)s;
    }
}

// ---------------- csr_window: hist + scan + dinv + rowstart + fill ----------------

__global__ __launch_bounds__(256) void csr_window(
        const unsigned* __restrict__ stage,
        const int* __restrict__ wcur,
        int* __restrict__ rowstart,   // [NNODES+1]
        float* __restrict__ dinv,     // [NNODES]
        int* __restrict__ csr) {
    __shared__ int cnt[WIN_NODES];
    __shared__ int red[256];
    const int w = blockIdx.x;
    const int t = threadIdx.x;
    const int wb = w * WIN_NODES;
    const size_t sb = (size_t)w * WCAP;

    int v = (t < w) ? min(wcur[t * WSTR], WCAP) : 0;
    red[t] = v;
    __syncthreads();
#pragma unroll
    for (int off = 128; off > 0; off >>= 1) {
        if (t < off) red[t] += red[t + off];
        __syncthreads();
    }
    int woff = red[0];
    int n_w = min(wcur[w * WSTR], WCAP);
    __syncthreads();

    for (int i = t; i < WIN_NODES; i += 256) cnt[i] = 0;
    __syncthreads();
    for (int i = t; i < n_w; i += 256)
        atomicAdd(&cnt[stage[sb + i] >> 17], 1);
    __syncthreads();

    int c0 = 0, c1 = 0, c2 = 0, c3 = 0, psum = 0;
    if (t < 250) {
        c0 = cnt[4 * t]; c1 = cnt[4 * t + 1]; c2 = cnt[4 * t + 2]; c3 = cnt[4 * t + 3];
        psum = c0 + c1 + c2 + c3;
    }
    red[t] = psum;
    __syncthreads();
#pragma unroll
    for (int off = 1; off < 256; off <<= 1) {
        int tv = (t >= off) ? red[t - off] : 0;
        __syncthreads();
        red[t] += tv;
        __syncthreads();
    }
    int excl = red[t] - psum;
    if (t < 250) {
        int running = woff + excl;
        int idx = 4 * t;
        rowstart[wb + idx] = running; dinv[wb + idx] = rsqrtf((float)c0 + 1.f);
        cnt[idx] = running; running += c0;
        rowstart[wb + idx + 1] = running; dinv[wb + idx + 1] = rsqrtf((float)c1 + 1.f);
        cnt[idx + 1] = running; running += c1;
        rowstart[wb + idx + 2] = running; dinv[wb + idx + 2] = rsqrtf((float)c2 + 1.f);
        cnt[idx + 2] = running; running += c2;
        rowstart[wb + idx + 3] = running; dinv[wb + idx + 3] = rsqrtf((float)c3 + 1.f);
        cnt[idx + 3] = running;
    }
    if (w == NWIN - 1 && t == 0) rowstart[NNODES] = woff + n_w;
    __syncthreads();

    for (int i = t; i < n_w; i += 256) {
        unsigned p = stage[sb + i];
        int dl = (int)(p >> 17);
        int s  = (int)(p & 0x1FFFFu);
        int pos = atomicAdd(&cnt[dl], 1);
        csr[pos] = s;
    }
}

// ---------------- gather64 + fused 64->16 transform (per-edge dinv) ----------------

__global__ __launch_bounds__(256) void gather64_l2(
        const int* __restrict__ rowstart, const int* __restrict__ csr,
        const float* __restrict__ dinv,
        const unsigned short* __restrict__ Hs1,   // [M,64] bf16 unscaled
        const float* __restrict__ b1,
        const float* __restrict__ W2,             // [64,16]
        unsigned short* __restrict__ Hs2,         // [M,16] bf16
        int M) {
    __shared__ float Ws2[64 * 16];
    __shared__ float b1s[64];
    __shared__ float srow[8][64];
    for (int i = threadIdx.x; i < 64 * 16; i += 256) Ws2[i] = W2[i];
    if (threadIdx.x < 64) b1s[threadIdx.x] = b1[threadIdx.x];
    __syncthreads();

    const int r = threadIdx.x >> 5;
    const int lf = threadIdx.x & 31;
    const int row = blockIdx.x * 8 + r;
    const bool rok = (row < M);

    float v0 = 0.f, v1 = 0.f;
    if (rok) {
        const unsigned* H32 = (const unsigned*)Hs1;
        int e0 = rowstart[row], e1 = rowstart[row + 1];
        float dd = dinv[row];
        float acc0, acc1;
        bfpair(H32[(size_t)row * 32 + lf], acc0, acc1);
        acc0 *= dd; acc1 *= dd;
        int e = e0;
        for (; e + 3 < e1; e += 4) {
            int s0 = csr[e], s1 = csr[e + 1], s2 = csr[e + 2], s3 = csr[e + 3];
            float w0 = dinv[s0], w1 = dinv[s1], w2 = dinv[s2], w3 = dinv[s3];
            unsigned u0 = H32[(size_t)s0 * 32 + lf];
            unsigned u1 = H32[(size_t)s1 * 32 + lf];
            unsigned u2 = H32[(size_t)s2 * 32 + lf];
            unsigned u3 = H32[(size_t)s3 * 32 + lf];
            float a, b;
            bfpair(u0, a, b); acc0 += w0 * a; acc1 += w0 * b;
            bfpair(u1, a, b); acc0 += w1 * a; acc1 += w1 * b;
            bfpair(u2, a, b); acc0 += w2 * a; acc1 += w2 * b;
            bfpair(u3, a, b); acc0 += w3 * a; acc1 += w3 * b;
        }
        for (; e < e1; e++) {
            int s0 = csr[e];
            float w0 = dinv[s0];
            unsigned u = H32[(size_t)s0 * 32 + lf];
            float a, b;
            bfpair(u, a, b); acc0 += w0 * a; acc1 += w0 * b;
        }
        v0 = fmaxf(acc0 * dd + b1s[2 * lf], 0.f);
        v1 = fmaxf(acc1 * dd + b1s[2 * lf + 1], 0.f);
    }
    float2 t2; t2.x = v0; t2.y = v1;
    *(float2*)&srow[r][2 * lf] = t2;
    __syncthreads();

    if (rok && lf < 16) {
        float acc = 0.f;
#pragma unroll
        for (int k4 = 0; k4 < 16; k4++) {
            float4 s4 = *(const float4*)&srow[r][k4 * 4];
            acc += s4.x * Ws2[(k4 * 4 + 0) * 16 + lf];
            acc += s4.y * Ws2[(k4 * 4 + 1) * 16 + lf];
            acc += s4.z * Ws2[(k4 * 4 + 2) * 16 + lf];
            acc += s4.w * Ws2[(k4 * 4 + 3) * 16 + lf];
        }
        acc *= dinv[row];
        float hi = __shfl_down(acc, 1, 64);
        if ((lf & 1) == 0) {
            unsigned p = (unsigned)f2bf(acc) | ((unsigned)f2bf(hi) << 16);
            ((unsigned*)Hs2)[(size_t)row * 8 + (lf >> 1)] = p;
        }
    }
}

// ---------------- generic CSR gather (layer-2 aggregation; input pre-scaled) ----------------

template <int F, bool RELU, bool SCALEOUT, bool HASBIAS, bool OUTBF>
__global__ __launch_bounds__(256) void gather_bf(
        const int* __restrict__ rowstart,
        const int* __restrict__ csr,
        const float* __restrict__ dinv,
        const unsigned short* __restrict__ Hs,
        const float* __restrict__ bias,
        void* __restrict__ outp,
        int M) {
    constexpr int LANES = F / 2;
    constexpr int GP = 256 / LANES;
    int row = blockIdx.x * GP + threadIdx.x / LANES;
    int lf = threadIdx.x % LANES;
    if (row >= M) return;

    const unsigned* H32 = (const unsigned*)Hs;
    const size_t LP = F / 2;

    int e0 = rowstart[row], e1 = rowstart[row + 1];
    float acc0, acc1;
    bfpair(H32[(size_t)row * LP + lf], acc0, acc1);

    int e = e0;
    for (; e + 3 < e1; e += 4) {
        int s0 = csr[e], s1 = csr[e + 1], s2 = csr[e + 2], s3 = csr[e + 3];
        unsigned u0 = H32[(size_t)s0 * LP + lf];
        unsigned u1 = H32[(size_t)s1 * LP + lf];
        unsigned u2 = H32[(size_t)s2 * LP + lf];
        unsigned u3 = H32[(size_t)s3 * LP + lf];
        float a, b;
        bfpair(u0, a, b); acc0 += a; acc1 += b;
        bfpair(u1, a, b); acc0 += a; acc1 += b;
        bfpair(u2, a, b); acc0 += a; acc1 += b;
        bfpair(u3, a, b); acc0 += a; acc1 += b;
    }
    for (; e < e1; e++) {
        unsigned u = H32[(size_t)csr[e] * LP + lf];
        float a, b;
        bfpair(u, a, b); acc0 += a; acc1 += b;
    }

    float dd = dinv[row];
    float v0 = acc0 * dd, v1 = acc1 * dd;
    if (HASBIAS) { v0 += bias[2 * lf]; v1 += bias[2 * lf + 1]; }
    if (RELU) { v0 = fmaxf(v0, 0.f); v1 = fmaxf(v1, 0.f); }
    if (SCALEOUT) { v0 *= dd; v1 *= dd; }
    if (OUTBF) {
        unsigned p = (unsigned)f2bf(v0) | ((unsigned)f2bf(v1) << 16);
        ((unsigned*)outp)[(size_t)row * LP + lf] = p;
    } else {
        float2 t; t.x = v0; t.y = v1;
        ((float2*)outp)[(size_t)row * LP + lf] = t;
    }
}

// ---------------- layer-3 aggregation + 16->40 matvec + log_softmax ----------------

#define SRP 20

__global__ __launch_bounds__(256) void gather16_final(
        const int* __restrict__ rowstart, const int* __restrict__ csr,
        const float* __restrict__ dinv,
        const unsigned short* __restrict__ r2s,   // [M,16] bf16 pre-scaled
        const float* __restrict__ W3,
        const float* __restrict__ b3,
        float* __restrict__ out,
        int M) {
    __shared__ float Ws3[16 * 40];
    __shared__ float bs3[40];
    __shared__ float srow[32][SRP];
    __shared__ float orow[32 * 40];
    for (int i = threadIdx.x; i < 16 * 40; i += 256) Ws3[i] = W3[i];
    if (threadIdx.x < 40) bs3[threadIdx.x] = b3[threadIdx.x];

    const int r = threadIdx.x >> 3;
    const int lf = threadIdx.x & 7;
    const int row = blockIdx.x * 32 + r;
    const bool rok = (row < M);

    float g0 = 0.f, g1 = 0.f;
    if (rok) {
        const unsigned* H32 = (const unsigned*)r2s;
        int e0 = rowstart[row], e1 = rowstart[row + 1];
        float acc0, acc1;
        bfpair(H32[(size_t)row * 8 + lf], acc0, acc1);
        int e = e0;
        for (; e + 3 < e1; e += 4) {
            int s0 = csr[e], s1 = csr[e + 1], s2 = csr[e + 2], s3 = csr[e + 3];
            unsigned u0 = H32[(size_t)s0 * 8 + lf];
            unsigned u1 = H32[(size_t)s1 * 8 + lf];
            unsigned u2 = H32[(size_t)s2 * 8 + lf];
            unsigned u3 = H32[(size_t)s3 * 8 + lf];
            float a, b;
            bfpair(u0, a, b); acc0 += a; acc1 += b;
            bfpair(u1, a, b); acc0 += a; acc1 += b;
            bfpair(u2, a, b); acc0 += a; acc1 += b;
            bfpair(u3, a, b); acc0 += a; acc1 += b;
        }
        for (; e < e1; e++) {
            unsigned u = H32[(size_t)csr[e] * 8 + lf];
            float a, b;
            bfpair(u, a, b); acc0 += a; acc1 += b;
        }
        float dd = dinv[row];
        g0 = acc0 * dd; g1 = acc1 * dd;
    }
    float2 t2; t2.x = g0; t2.y = g1;
    *(float2*)&srow[r][2 * lf] = t2;
    __syncthreads();

    float vals[5];
#pragma unroll
    for (int q = 0; q < 5; q++) vals[q] = bs3[lf + 8 * q];
#pragma unroll
    for (int k4 = 0; k4 < 4; k4++) {
        float4 s4 = *(const float4*)&srow[r][k4 * 4];
#pragma unroll
        for (int q = 0; q < 5; q++) {
            int n = lf + 8 * q;
            vals[q] += s4.x * Ws3[(k4 * 4 + 0) * 40 + n];
            vals[q] += s4.y * Ws3[(k4 * 4 + 1) * 40 + n];
            vals[q] += s4.z * Ws3[(k4 * 4 + 2) * 40 + n];
            vals[q] += s4.w * Ws3[(k4 * 4 + 3) * 40 + n];
        }
    }
    float m = vals[0];
#pragma unroll
    for (int q = 1; q < 5; q++) m = fmaxf(m, vals[q]);
#pragma unroll
    for (int off = 1; off < 8; off <<= 1) m = fmaxf(m, __shfl_xor(m, off, 64));
    float s = 0.f;
#pragma unroll
    for (int q = 0; q < 5; q++) s += expf(vals[q] - m);
#pragma unroll
    for (int off = 1; off < 8; off <<= 1) s += __shfl_xor(s, off, 64);
    float ls = logf(s) + m;
#pragma unroll
    for (int q = 0; q < 5; q++) orow[r * 40 + lf + 8 * q] = vals[q] - ls;
    __syncthreads();

    float4* o4 = (float4*)(out + (size_t)blockIdx.x * 32 * 40);
    const float4* s4p = (const float4*)orow;
    for (int i = threadIdx.x; i < 320; i += 256) {
        int rr = (i * 4) / 40;
        if (blockIdx.x * 32 + rr < M) o4[i] = s4p[i];
    }
}

// ---------------- launch ----------------

extern "C" void kernel_launch(void* const* d_in, const int* in_sizes, int n_in,
                              void* d_out, int out_size, void* d_ws, size_t ws_size,
                              hipStream_t stream) {
    const float* x   = (const float*)d_in[0];
    const int*   ei  = (const int*)d_in[1];
    const int*   src = ei;
    const int*   dst = ei + NEDGES;
    const float* W1 = (const float*)d_in[2];
    const float* b1 = (const float*)d_in[3];
    const float* W2 = (const float*)d_in[4];
    const float* b2 = (const float*)d_in[5];
    const float* W3 = (const float*)d_in[6];
    const float* b3 = (const float*)d_in[7];
    float* out = (float*)d_out;

    int* ws_i = (int*)d_ws;
    int* wcur     = ws_i;                        // NWIN*WSTR
    int* rowstart = wcur + NWIN * WSTR + 16;     // N+8
    int* csr      = rowstart + NNODES + 8;       // E
    unsigned* stage = (unsigned*)(csr + NEDGES); // NWIN*WCAP
    float* dinv   = (float*)(stage + (size_t)NWIN * WCAP);  // N
    unsigned short* Wt = (unsigned short*)(dinv + NNODES);  // 64*512 bf16
    float* bufA   = (float*)((int*)(Wt + 64 * 512) + 16);
    float* bufB   = bufA + (size_t)NNODES * 64;

    unsigned short* Hs1 = (unsigned short*)bufA;   // [N,64] bf16 unscaled
    unsigned short* Hs2 = (unsigned short*)bufB;   // [N,16] bf16
    unsigned short* r2s = (unsigned short*)bufA;   // [N,16] bf16 (Hs1 dead)

    // --- W1 -> bf16^T + wcur zero ---
    convW<<<128, 256, 0, stream>>>(W1, Wt, wcur);

    // --- SPLIT: GEMM alone (full machine), then bucketing alone ---
    gemm_k<<<GEMM_BLOCKS, 256, 0, stream>>>(x, Wt, Hs1, NNODES);
    bucket_k<<<BUCKET_BLOCKS, 256, 0, stream>>>(src, dst, stage, wcur, NEDGES);

    // --- CSR finalize: one block per window ---
    csr_window<<<NWIN, 256, 0, stream>>>(stage, wcur, rowstart, dinv, csr);

    // --- layer-1 aggregation (per-edge dinv) + fused 64->16 transform ---
    gather64_l2<<<(NNODES + 7) / 8, 256, 0, stream>>>(
        rowstart, csr, dinv, Hs1, b1, W2, Hs2, NNODES);

    // --- layer-2 aggregation (relu + b2 + pre-scale) ---
    gather_bf<16, true, true, true, true><<<(NNODES + 31) / 32, 256, 0, stream>>>(
        rowstart, csr, dinv, Hs2, b2, r2s, NNODES);

    // --- layer-3 aggregation + 16->40 matvec + log_softmax ---
    gather16_final<<<(NNODES + 31) / 32, 256, 0, stream>>>(
        rowstart, csr, dinv, r2s, W3, b3, out, NNODES);
}

// Round 15
// 202.079 us; speedup vs baseline: 2.6021x; 1.0693x over previous
//
#include <hip/hip_runtime.h>
#include <cstdint>
#include <cstddef>

#define NNODES 100000
#define NEDGES 1600000
#define NWIN 100
#define WIN_NODES 1000
#define WCAP 17408
#define WSTR 16

#define GM_ROWS 64
#define APAD 72
#define GEMM_BLOCKS ((NNODES + GM_ROWS - 1) / GM_ROWS)   // 1563
#define BUCKET_BLOCKS 512
#define BCHUNK ((NEDGES + BUCKET_BLOCKS - 1) / BUCKET_BLOCKS)  // 3125
#define MEGA_BLOCKS (GEMM_BLOCKS + BUCKET_BLOCKS)        // 2075

typedef __attribute__((ext_vector_type(8))) short bf16x8;
typedef __attribute__((ext_vector_type(4))) float f32x4;
typedef __attribute__((ext_vector_type(8))) unsigned short ushort8v;

__device__ inline unsigned short f2bf(float f) {
    union { float f; unsigned u; } v; v.f = f;
    unsigned r = v.u + 0x7FFFu + ((v.u >> 16) & 1u);   // RNE
    return (unsigned short)(r >> 16);
}
__device__ inline void bfpair(unsigned u, float& lo, float& hi) {
    union { unsigned x; float f; } a, b;
    a.x = u << 16; b.x = u & 0xffff0000u;
    lo = a.f; hi = b.f;
}

// ---------------- W1 convert+transpose (+ wcur zero) ----------------

__global__ __launch_bounds__(256) void convW(const float* __restrict__ W,
                                             unsigned short* __restrict__ Wt,
                                             int* __restrict__ wcur) {
    if (blockIdx.x == 0 && threadIdx.x < NWIN) wcur[threadIdx.x * WSTR] = 0;
    int i = blockIdx.x * 256 + threadIdx.x;
    if (i < 512 * 64) {
        int k = i >> 6, n = i & 63;
        Wt[n * 512 + k] = f2bf(W[i]);
    }
}

// ---------------- MEGA kernel: GEMM role (64-row tiles) + edge-bucketing role ----------------
// r9 merged structure (best known: overlap worth ~15us) with GM_ROWS halved:
// 1563 GEMM blocks (~8 blocks/CU with bucket) instead of 782 (~3/CU) — the
// occupancy was grid-starved, not resource-capped (r7/r13 Occupancy~33%).

__global__ __launch_bounds__(256) void mega_gemm_bucket(
        const float* __restrict__ A,            // [M,512] x
        const unsigned short* __restrict__ Wt,  // [64][512] bf16
        unsigned short* __restrict__ Hs,        // [M,64] bf16 UNSCALED out
        const int* __restrict__ src, const int* __restrict__ dst,
        unsigned* __restrict__ stage,
        int* __restrict__ wcur, int M, int E) {
    __shared__ __align__(16) unsigned char smem[9216 + 9216];

    long long b = blockIdx.x;
    int g0 = (int)((b * GEMM_BLOCKS) / MEGA_BLOCKS);
    int g1 = (int)(((b + 1) * GEMM_BLOCKS) / MEGA_BLOCKS);

    if (g1 > g0) {
        // ---------------- GEMM role: 64 rows/block, 16 rows/wave ----------------
        typedef unsigned short RowA[APAD];
        RowA* As = (RowA*)smem;                 // [64][72]
        RowA* Bs = (RowA*)(smem + 9216);        // [64][72]
        const int tid = threadIdx.x;
        const int wid = tid >> 6;
        const int lane = tid & 63;
        const int bm = g0 * GM_ROWS;

        f32x4 acc[4];
#pragma unroll
        for (int j = 0; j < 4; j++) acc[j] = (f32x4){0.f, 0.f, 0.f, 0.f};

        const int ar = tid >> 4;        // 0..15
        const int ac4 = tid & 15;
        const int lm = lane & 15;
        const int lk = (lane >> 4) * 8;

        float4 aR0[4], aR1[4];
        ushort8v bR0[2], bR1[2];

        auto LOADA = [&](float4 (&aRx)[4], ushort8v (&bRx)[2], int k0) {
#pragma unroll
            for (int p = 0; p < 4; p++) {
                int row = bm + p * 16 + ar;
                if (row < M) aRx[p] = *(const float4*)&A[(size_t)row * 512 + k0 + ac4 * 4];
                else         aRx[p] = make_float4(0.f, 0.f, 0.f, 0.f);
            }
#pragma unroll
            for (int p = 0; p < 2; p++) {
                int c = p * 256 + tid;
                int n = c >> 3, kc = c & 7;
                bRx[p] = *(const ushort8v*)&Wt[(size_t)n * 512 + k0 + kc * 8];
            }
        };

        auto TILE = [&](float4 (&aRx)[4], ushort8v (&bRx)[2], int k0) {
#pragma unroll
            for (int p = 0; p < 4; p++) {
                int r = p * 16 + ar;
                unsigned lo, hi;
                asm("v_cvt_pk_bf16_f32 %0, %1, %2" : "=v"(lo) : "v"(aRx[p].x), "v"(aRx[p].y));
                asm("v_cvt_pk_bf16_f32 %0, %1, %2" : "=v"(hi) : "v"(aRx[p].z), "v"(aRx[p].w));
                uint2 u; u.x = lo; u.y = hi;
                *(uint2*)&As[r][ac4 * 4] = u;
            }
#pragma unroll
            for (int p = 0; p < 2; p++) {
                int c = p * 256 + tid;
                int n = c >> 3, kc = c & 7;
                *(ushort8v*)&Bs[n][kc * 8] = bRx[p];
            }
            __syncthreads();

            if (k0 + 128 < 512) LOADA(aRx, bRx, k0 + 128);   // 2-tile-ahead prefetch

            bf16x8 af[2], bb[4][2];
#pragma unroll
            for (int kf = 0; kf < 2; kf++)
                af[kf] = *(const bf16x8*)&As[wid * 16 + lm][kf * 32 + lk];
#pragma unroll
            for (int cf = 0; cf < 4; cf++)
#pragma unroll
                for (int kf = 0; kf < 2; kf++)
                    bb[cf][kf] = *(const bf16x8*)&Bs[cf * 16 + lm][kf * 32 + lk];

            __builtin_amdgcn_s_setprio(1);
#pragma unroll
            for (int kf = 0; kf < 2; kf++)
#pragma unroll
                for (int cf = 0; cf < 4; cf++)
                    acc[cf] = __builtin_amdgcn_mfma_f32_16x16x32_bf16(
                        af[kf], bb[cf][kf], acc[cf], 0, 0, 0);
            __builtin_amdgcn_s_setprio(0);
            __syncthreads();
        };

        LOADA(aR0, bR0, 0);
        LOADA(aR1, bR1, 64);
        for (int tp = 0; tp < 4; tp++) {
            TILE(aR0, bR0, tp * 128);
            TILE(aR1, bR1, tp * 128 + 64);
        }

        // epilogue: D col = lane&15, row = (lane>>4)*4 + j
#pragma unroll
        for (int j = 0; j < 4; j++) {
            int row = bm + wid * 16 + (lane >> 4) * 4 + j;
            if (row < M) {
#pragma unroll
                for (int cf = 0; cf < 4; cf++)
                    Hs[(size_t)row * 64 + cf * 16 + lm] = f2bf(acc[cf][j]);
            }
        }
    } else {
        // ---------------- bucket role ----------------
        int bi = (int)(b - g0);
        int* cnt  = (int*)smem;
        int* lcur = cnt + NWIN;
        const int tid = threadIdx.x;
        int e0 = bi * BCHUNK;
        int e1 = e0 + BCHUNK; if (e1 > E) e1 = E;

        for (int i = tid; i < NWIN; i += 256) cnt[i] = 0;
        __syncthreads();
        for (int e = e0 + tid; e < e1; e += 256)
            atomicAdd(&cnt[dst[e] / WIN_NODES], 1);
        __syncthreads();
        for (int i = tid; i < NWIN; i += 256)
            lcur[i] = atomicAdd(&wcur[i * WSTR], cnt[i]);
        __syncthreads();
        for (int e = e0 + tid; e < e1; e += 256) {
            int d = dst[e], s = src[e];
            int w = d / WIN_NODES;
            int pos = atomicAdd(&lcur[w], 1);
            if (pos < WCAP)
                stage[(size_t)w * WCAP + pos] =
                    ((unsigned)(d - w * WIN_NODES) << 17) | (unsigned)s;
        }
    }
}

// ---------------- csr_window: hist + scan + dinv + rowstart + fill ----------------

__global__ __launch_bounds__(256) void csr_window(
        const unsigned* __restrict__ stage,
        const int* __restrict__ wcur,
        int* __restrict__ rowstart,   // [NNODES+1]
        float* __restrict__ dinv,     // [NNODES]
        int* __restrict__ csr) {
    __shared__ int cnt[WIN_NODES];
    __shared__ int red[256];
    const int w = blockIdx.x;
    const int t = threadIdx.x;
    const int wb = w * WIN_NODES;
    const size_t sb = (size_t)w * WCAP;

    int v = (t < w) ? min(wcur[t * WSTR], WCAP) : 0;
    red[t] = v;
    __syncthreads();
#pragma unroll
    for (int off = 128; off > 0; off >>= 1) {
        if (t < off) red[t] += red[t + off];
        __syncthreads();
    }
    int woff = red[0];
    int n_w = min(wcur[w * WSTR], WCAP);
    __syncthreads();

    for (int i = t; i < WIN_NODES; i += 256) cnt[i] = 0;
    __syncthreads();
    for (int i = t; i < n_w; i += 256)
        atomicAdd(&cnt[stage[sb + i] >> 17], 1);
    __syncthreads();

    int c0 = 0, c1 = 0, c2 = 0, c3 = 0, psum = 0;
    if (t < 250) {
        c0 = cnt[4 * t]; c1 = cnt[4 * t + 1]; c2 = cnt[4 * t + 2]; c3 = cnt[4 * t + 3];
        psum = c0 + c1 + c2 + c3;
    }
    red[t] = psum;
    __syncthreads();
#pragma unroll
    for (int off = 1; off < 256; off <<= 1) {
        int tv = (t >= off) ? red[t - off] : 0;
        __syncthreads();
        red[t] += tv;
        __syncthreads();
    }
    int excl = red[t] - psum;
    if (t < 250) {
        int running = woff + excl;
        int idx = 4 * t;
        rowstart[wb + idx] = running; dinv[wb + idx] = rsqrtf((float)c0 + 1.f);
        cnt[idx] = running; running += c0;
        rowstart[wb + idx + 1] = running; dinv[wb + idx + 1] = rsqrtf((float)c1 + 1.f);
        cnt[idx + 1] = running; running += c1;
        rowstart[wb + idx + 2] = running; dinv[wb + idx + 2] = rsqrtf((float)c2 + 1.f);
        cnt[idx + 2] = running; running += c2;
        rowstart[wb + idx + 3] = running; dinv[wb + idx + 3] = rsqrtf((float)c3 + 1.f);
        cnt[idx + 3] = running;
    }
    if (w == NWIN - 1 && t == 0) rowstart[NNODES] = woff + n_w;
    __syncthreads();

    for (int i = t; i < n_w; i += 256) {
        unsigned p = stage[sb + i];
        int dl = (int)(p >> 17);
        int s  = (int)(p & 0x1FFFFu);
        int pos = atomicAdd(&cnt[dl], 1);
        csr[pos] = s;
    }
}

// ---------------- gather64 + fused 64->16 transform (per-edge dinv) ----------------

__global__ __launch_bounds__(256) void gather64_l2(
        const int* __restrict__ rowstart, const int* __restrict__ csr,
        const float* __restrict__ dinv,
        const unsigned short* __restrict__ Hs1,   // [M,64] bf16 unscaled
        const float* __restrict__ b1,
        const float* __restrict__ W2,             // [64,16]
        unsigned short* __restrict__ Hs2,         // [M,16] bf16
        int M) {
    __shared__ float Ws2[64 * 16];
    __shared__ float b1s[64];
    __shared__ float srow[8][64];
    for (int i = threadIdx.x; i < 64 * 16; i += 256) Ws2[i] = W2[i];
    if (threadIdx.x < 64) b1s[threadIdx.x] = b1[threadIdx.x];
    __syncthreads();

    const int r = threadIdx.x >> 5;
    const int lf = threadIdx.x & 31;
    const int row = blockIdx.x * 8 + r;
    const bool rok = (row < M);

    float v0 = 0.f, v1 = 0.f;
    if (rok) {
        const unsigned* H32 = (const unsigned*)Hs1;
        int e0 = rowstart[row], e1 = rowstart[row + 1];
        float dd = dinv[row];
        float acc0, acc1;
        bfpair(H32[(size_t)row * 32 + lf], acc0, acc1);
        acc0 *= dd; acc1 *= dd;
        int e = e0;
        for (; e + 3 < e1; e += 4) {
            int s0 = csr[e], s1 = csr[e + 1], s2 = csr[e + 2], s3 = csr[e + 3];
            float w0 = dinv[s0], w1 = dinv[s1], w2 = dinv[s2], w3 = dinv[s3];
            unsigned u0 = H32[(size_t)s0 * 32 + lf];
            unsigned u1 = H32[(size_t)s1 * 32 + lf];
            unsigned u2 = H32[(size_t)s2 * 32 + lf];
            unsigned u3 = H32[(size_t)s3 * 32 + lf];
            float a, b;
            bfpair(u0, a, b); acc0 += w0 * a; acc1 += w0 * b;
            bfpair(u1, a, b); acc0 += w1 * a; acc1 += w1 * b;
            bfpair(u2, a, b); acc0 += w2 * a; acc1 += w2 * b;
            bfpair(u3, a, b); acc0 += w3 * a; acc1 += w3 * b;
        }
        for (; e < e1; e++) {
            int s0 = csr[e];
            float w0 = dinv[s0];
            unsigned u = H32[(size_t)s0 * 32 + lf];
            float a, b;
            bfpair(u, a, b); acc0 += w0 * a; acc1 += w0 * b;
        }
        v0 = fmaxf(acc0 * dd + b1s[2 * lf], 0.f);
        v1 = fmaxf(acc1 * dd + b1s[2 * lf + 1], 0.f);
    }
    float2 t2; t2.x = v0; t2.y = v1;
    *(float2*)&srow[r][2 * lf] = t2;
    __syncthreads();

    if (rok && lf < 16) {
        float acc = 0.f;
#pragma unroll
        for (int k4 = 0; k4 < 16; k4++) {
            float4 s4 = *(const float4*)&srow[r][k4 * 4];
            acc += s4.x * Ws2[(k4 * 4 + 0) * 16 + lf];
            acc += s4.y * Ws2[(k4 * 4 + 1) * 16 + lf];
            acc += s4.z * Ws2[(k4 * 4 + 2) * 16 + lf];
            acc += s4.w * Ws2[(k4 * 4 + 3) * 16 + lf];
        }
        acc *= dinv[row];
        float hi = __shfl_down(acc, 1, 64);
        if ((lf & 1) == 0) {
            unsigned p = (unsigned)f2bf(acc) | ((unsigned)f2bf(hi) << 16);
            ((unsigned*)Hs2)[(size_t)row * 8 + (lf >> 1)] = p;
        }
    }
}

// ---------------- generic CSR gather (layer-2 aggregation; input pre-scaled) ----------------

template <int F, bool RELU, bool SCALEOUT, bool HASBIAS, bool OUTBF>
__global__ __launch_bounds__(256) void gather_bf(
        const int* __restrict__ rowstart,
        const int* __restrict__ csr,
        const float* __restrict__ dinv,
        const unsigned short* __restrict__ Hs,
        const float* __restrict__ bias,
        void* __restrict__ outp,
        int M) {
    constexpr int LANES = F / 2;
    constexpr int GP = 256 / LANES;
    int row = blockIdx.x * GP + threadIdx.x / LANES;
    int lf = threadIdx.x % LANES;
    if (row >= M) return;

    const unsigned* H32 = (const unsigned*)Hs;
    const size_t LP = F / 2;

    int e0 = rowstart[row], e1 = rowstart[row + 1];
    float acc0, acc1;
    bfpair(H32[(size_t)row * LP + lf], acc0, acc1);

    int e = e0;
    for (; e + 3 < e1; e += 4) {
        int s0 = csr[e], s1 = csr[e + 1], s2 = csr[e + 2], s3 = csr[e + 3];
        unsigned u0 = H32[(size_t)s0 * LP + lf];
        unsigned u1 = H32[(size_t)s1 * LP + lf];
        unsigned u2 = H32[(size_t)s2 * LP + lf];
        unsigned u3 = H32[(size_t)s3 * LP + lf];
        float a, b;
        bfpair(u0, a, b); acc0 += a; acc1 += b;
        bfpair(u1, a, b); acc0 += a; acc1 += b;
        bfpair(u2, a, b); acc0 += a; acc1 += b;
        bfpair(u3, a, b); acc0 += a; acc1 += b;
    }
    for (; e < e1; e++) {
        unsigned u = H32[(size_t)csr[e] * LP + lf];
        float a, b;
        bfpair(u, a, b); acc0 += a; acc1 += b;
    }

    float dd = dinv[row];
    float v0 = acc0 * dd, v1 = acc1 * dd;
    if (HASBIAS) { v0 += bias[2 * lf]; v1 += bias[2 * lf + 1]; }
    if (RELU) { v0 = fmaxf(v0, 0.f); v1 = fmaxf(v1, 0.f); }
    if (SCALEOUT) { v0 *= dd; v1 *= dd; }
    if (OUTBF) {
        unsigned p = (unsigned)f2bf(v0) | ((unsigned)f2bf(v1) << 16);
        ((unsigned*)outp)[(size_t)row * LP + lf] = p;
    } else {
        float2 t; t.x = v0; t.y = v1;
        ((float2*)outp)[(size_t)row * LP + lf] = t;
    }
}

// ---------------- layer-3 aggregation + 16->40 matvec + log_softmax ----------------

#define SRP 20

__global__ __launch_bounds__(256) void gather16_final(
        const int* __restrict__ rowstart, const int* __restrict__ csr,
        const float* __restrict__ dinv,
        const unsigned short* __restrict__ r2s,   // [M,16] bf16 pre-scaled
        const float* __restrict__ W3,
        const float* __restrict__ b3,
        float* __restrict__ out,
        int M) {
    __shared__ float Ws3[16 * 40];
    __shared__ float bs3[40];
    __shared__ float srow[32][SRP];
    __shared__ float orow[32 * 40];
    for (int i = threadIdx.x; i < 16 * 40; i += 256) Ws3[i] = W3[i];
    if (threadIdx.x < 40) bs3[threadIdx.x] = b3[threadIdx.x];

    const int r = threadIdx.x >> 3;
    const int lf = threadIdx.x & 7;
    const int row = blockIdx.x * 32 + r;
    const bool rok = (row < M);

    float g0 = 0.f, g1 = 0.f;
    if (rok) {
        const unsigned* H32 = (const unsigned*)r2s;
        int e0 = rowstart[row], e1 = rowstart[row + 1];
        float acc0, acc1;
        bfpair(H32[(size_t)row * 8 + lf], acc0, acc1);
        int e = e0;
        for (; e + 3 < e1; e += 4) {
            int s0 = csr[e], s1 = csr[e + 1], s2 = csr[e + 2], s3 = csr[e + 3];
            unsigned u0 = H32[(size_t)s0 * 8 + lf];
            unsigned u1 = H32[(size_t)s1 * 8 + lf];
            unsigned u2 = H32[(size_t)s2 * 8 + lf];
            unsigned u3 = H32[(size_t)s3 * 8 + lf];
            float a, b;
            bfpair(u0, a, b); acc0 += a; acc1 += b;
            bfpair(u1, a, b); acc0 += a; acc1 += b;
            bfpair(u2, a, b); acc0 += a; acc1 += b;
            bfpair(u3, a, b); acc0 += a; acc1 += b;
        }
        for (; e < e1; e++) {
            unsigned u = H32[(size_t)csr[e] * 8 + lf];
            float a, b;
            bfpair(u, a, b); acc0 += a; acc1 += b;
        }
        float dd = dinv[row];
        g0 = acc0 * dd; g1 = acc1 * dd;
    }
    float2 t2; t2.x = g0; t2.y = g1;
    *(float2*)&srow[r][2 * lf] = t2;
    __syncthreads();

    float vals[5];
#pragma unroll
    for (int q = 0; q < 5; q++) vals[q] = bs3[lf + 8 * q];
#pragma unroll
    for (int k4 = 0; k4 < 4; k4++) {
        float4 s4 = *(const float4*)&srow[r][k4 * 4];
#pragma unroll
        for (int q = 0; q < 5; q++) {
            int n = lf + 8 * q;
            vals[q] += s4.x * Ws3[(k4 * 4 + 0) * 40 + n];
            vals[q] += s4.y * Ws3[(k4 * 4 + 1) * 40 + n];
            vals[q] += s4.z * Ws3[(k4 * 4 + 2) * 40 + n];
            vals[q] += s4.w * Ws3[(k4 * 4 + 3) * 40 + n];
        }
    }
    float m = vals[0];
#pragma unroll
    for (int q = 1; q < 5; q++) m = fmaxf(m, vals[q]);
#pragma unroll
    for (int off = 1; off < 8; off <<= 1) m = fmaxf(m, __shfl_xor(m, off, 64));
    float s = 0.f;
#pragma unroll
    for (int q = 0; q < 5; q++) s += expf(vals[q] - m);
#pragma unroll
    for (int off = 1; off < 8; off <<= 1) s += __shfl_xor(s, off, 64);
    float ls = logf(s) + m;
#pragma unroll
    for (int q = 0; q < 5; q++) orow[r * 40 + lf + 8 * q] = vals[q] - ls;
    __syncthreads();

    float4* o4 = (float4*)(out + (size_t)blockIdx.x * 32 * 40);
    const float4* s4p = (const float4*)orow;
    for (int i = threadIdx.x; i < 320; i += 256) {
        int rr = (i * 4) / 40;
        if (blockIdx.x * 32 + rr < M) o4[i] = s4p[i];
    }
}

// ---------------- launch ----------------

extern "C" void kernel_launch(void* const* d_in, const int* in_sizes, int n_in,
                              void* d_out, int out_size, void* d_ws, size_t ws_size,
                              hipStream_t stream) {
    const float* x   = (const float*)d_in[0];
    const int*   ei  = (const int*)d_in[1];
    const int*   src = ei;
    const int*   dst = ei + NEDGES;
    const float* W1 = (const float*)d_in[2];
    const float* b1 = (const float*)d_in[3];
    const float* W2 = (const float*)d_in[4];
    const float* b2 = (const float*)d_in[5];
    const float* W3 = (const float*)d_in[6];
    const float* b3 = (const float*)d_in[7];
    float* out = (float*)d_out;

    int* ws_i = (int*)d_ws;
    int* wcur     = ws_i;                        // NWIN*WSTR
    int* rowstart = wcur + NWIN * WSTR + 16;     // N+8
    int* csr      = rowstart + NNODES + 8;       // E
    unsigned* stage = (unsigned*)(csr + NEDGES); // NWIN*WCAP
    float* dinv   = (float*)(stage + (size_t)NWIN * WCAP);  // N
    unsigned short* Wt = (unsigned short*)(dinv + NNODES);  // 64*512 bf16
    float* bufA   = (float*)((int*)(Wt + 64 * 512) + 16);
    float* bufB   = bufA + (size_t)NNODES * 64;

    unsigned short* Hs1 = (unsigned short*)bufA;   // [N,64] bf16 unscaled
    unsigned short* Hs2 = (unsigned short*)bufB;   // [N,16] bf16
    unsigned short* r2s = (unsigned short*)bufA;   // [N,16] bf16 (Hs1 dead)

    // --- W1 -> bf16^T + wcur zero ---
    convW<<<128, 256, 0, stream>>>(W1, Wt, wcur);

    // --- MEGA: GEMM (64-row tiles) overlapped with edge bucketing ---
    mega_gemm_bucket<<<MEGA_BLOCKS, 256, 0, stream>>>(
        x, Wt, Hs1, src, dst, stage, wcur, NNODES, NEDGES);

    // --- CSR finalize: one block per window ---
    csr_window<<<NWIN, 256, 0, stream>>>(stage, wcur, rowstart, dinv, csr);

    // --- layer-1 aggregation (per-edge dinv) + fused 64->16 transform ---
    gather64_l2<<<(NNODES + 7) / 8, 256, 0, stream>>>(
        rowstart, csr, dinv, Hs1, b1, W2, Hs2, NNODES);

    // --- layer-2 aggregation (relu + b2 + pre-scale) ---
    gather_bf<16, true, true, true, true><<<(NNODES + 31) / 32, 256, 0, stream>>>(
        rowstart, csr, dinv, Hs2, b2, r2s, NNODES);

    // --- layer-3 aggregation + 16->40 matvec + log_softmax ---
    gather16_final<<<(NNODES + 31) / 32, 256, 0, stream>>>(
        rowstart, csr, dinv, r2s, W3, b3, out, NNODES);
}